// Round 1
// baseline (306.455 us; speedup 1.0000x reference)
//
#include <hip/hip_runtime.h>

// Problem dims (fixed by reference)
#define BB 4
#define ENC_LEN 1024
#define DEC_LEN 256
#define ENC_H 1024
#define ATTN_A 256

// ---------------------------------------------------------------------------
// Generic fp32 tiled GEMM: C = A(MxK) * B(KxN) [+ bias]
// 64x64 tile, BK=16, 256 threads, 4x4 microtile per thread.
// OMODE 0: C[row*ldc+col] (batched via sA/sB/sC pointer strides)
// OMODE 1: rows are collapsed (b*1024+e); write C[b][col][e] (proj_enc^T)
// ---------------------------------------------------------------------------
template <int OMODE, bool BIAS>
__global__ __launch_bounds__(256) void gemm64(const float* __restrict__ A,
                                              const float* __restrict__ B,
                                              const float* __restrict__ bias,
                                              float* __restrict__ C,
                                              int K, int lda, int ldb, int ldc,
                                              long sA, long sB, long sC) {
  const int bz = blockIdx.z;
  A += (long)bz * sA;
  B += (long)bz * sB;
  C += (long)bz * sC;

  const int tid = threadIdx.x;
  const int tx = tid & 15;   // n-dir
  const int ty = tid >> 4;   // m-dir

  __shared__ float As[16][64];  // [k][m]
  __shared__ float Bs[16][64];  // [k][n]

  float acc[4][4];
#pragma unroll
  for (int i = 0; i < 4; ++i)
#pragma unroll
    for (int j = 0; j < 4; ++j) acc[i][j] = 0.f;

  // A-tile load mapping: 64 rows x 16 k, 4 floats per thread (float4 on k)
  const int ar = tid >> 2;          // 0..63 (m)
  const int ak4 = (tid & 3) << 2;   // 0,4,8,12 (k)
  // B-tile load mapping: 16 k x 64 n, float4 on n
  const int br = tid >> 4;          // 0..15 (k)
  const int bn4 = (tid & 15) << 2;  // 0..60 (n)

  const float* Aload = A + (long)(blockIdx.y * 64 + ar) * lda + ak4;
  const float* Bload = B + (long)br * ldb + blockIdx.x * 64 + bn4;

  for (int k0 = 0; k0 < K; k0 += 16) {
    const float4 av = *(const float4*)(Aload + k0);
    const float4 bv = *(const float4*)(Bload + (long)k0 * ldb);
    __syncthreads();  // previous tile fully consumed
    As[ak4 + 0][ar] = av.x;
    As[ak4 + 1][ar] = av.y;
    As[ak4 + 2][ar] = av.z;
    As[ak4 + 3][ar] = av.w;
    *(float4*)&Bs[br][bn4] = bv;
    __syncthreads();
#pragma unroll
    for (int kk = 0; kk < 16; ++kk) {
      const float4 a4 = *(const float4*)&As[kk][ty << 2];
      const float4 b4 = *(const float4*)&Bs[kk][tx << 2];
      const float am[4] = {a4.x, a4.y, a4.z, a4.w};
      const float bn[4] = {b4.x, b4.y, b4.z, b4.w};
#pragma unroll
      for (int i = 0; i < 4; ++i)
#pragma unroll
        for (int j = 0; j < 4; ++j) acc[i][j] = fmaf(am[i], bn[j], acc[i][j]);
    }
  }

  if (OMODE == 0) {
    const int row0 = blockIdx.y * 64 + (ty << 2);
    const int col0 = blockIdx.x * 64 + (tx << 2);
    float4 bb4 = make_float4(0.f, 0.f, 0.f, 0.f);
    if (BIAS) bb4 = *(const float4*)&bias[col0];
#pragma unroll
    for (int i = 0; i < 4; ++i) {
      float4 o;
      o.x = acc[i][0] + bb4.x;
      o.y = acc[i][1] + bb4.y;
      o.z = acc[i][2] + bb4.z;
      o.w = acc[i][3] + bb4.w;
      *(float4*)&C[(long)(row0 + i) * ldc + col0] = o;
    }
  } else {
    // rows collapsed over (b,e); write C[b][col][e], b stride 256*1024
#pragma unroll
    for (int i = 0; i < 4; ++i) {
      const int gr = blockIdx.y * 64 + (ty << 2) + i;
      const int b = gr >> 10;
      const int e = gr & 1023;
#pragma unroll
      for (int j = 0; j < 4; ++j) {
        const int col = blockIdx.x * 64 + (tx << 2) + j;
        C[(long)b * (ATTN_A * ENC_LEN) + (long)col * ENC_LEN + e] = acc[i][j];
      }
    }
  }
}

// ---------------------------------------------------------------------------
// Logits: logit[b,d,e] = sum_a v[a]*tanh(pd[b,d,a] + peT[b,a,e])  (up to a
// constant sum_v which cancels in softmax; we accumulate -2*v[a]/(e^{2x}+1)).
// Grid: (ENC/256, DEC/4, B), 256 threads; thread = one e, 4 d's.
// ---------------------------------------------------------------------------
__global__ __launch_bounds__(256) void logits_k(const float* __restrict__ peT,
                                                const float* __restrict__ pd,
                                                const float* __restrict__ v,
                                                float* __restrict__ out) {
  const int tid = threadIdx.x;
  const int e = blockIdx.x * 256 + tid;
  const int d0 = blockIdx.y * 4;
  const int b = blockIdx.z;

  // exp(2x) = exp2(C2*x), C2 = 2*log2(e)
  const float C2 = 2.8853900817779268f;

  __shared__ float cpd[ATTN_A * 4];  // [a][dd] packed for b128 broadcast reads
  __shared__ float vv[ATTN_A];       // -2*v[a]

#pragma unroll
  for (int dd = 0; dd < 4; ++dd)
    cpd[tid * 4 + dd] = C2 * pd[((b * DEC_LEN + d0 + dd) * ATTN_A) + tid];
  vv[tid] = -2.0f * v[tid];
  __syncthreads();

  float acc0 = 0.f, acc1 = 0.f, acc2 = 0.f, acc3 = 0.f;
  const float* pe = peT + (long)b * (ATTN_A * ENC_LEN) + e;

  for (int a4 = 0; a4 < ATTN_A; a4 += 4) {
    const float4 v4 = *(const float4*)&vv[a4];
    const float pe0 = pe[0 * ENC_LEN];
    const float pe1 = pe[1 * ENC_LEN];
    const float pe2 = pe[2 * ENC_LEN];
    const float pe3 = pe[3 * ENC_LEN];
    pe += 4 * ENC_LEN;
    const float pes[4] = {pe0, pe1, pe2, pe3};
    const float vs[4] = {v4.x, v4.y, v4.z, v4.w};
#pragma unroll
    for (int u = 0; u < 4; ++u) {
      const float cpe = C2 * pes[u];
      const float4 cp = *(const float4*)&cpd[(a4 + u) * 4];
      float x, ex, r;
      x = cp.x + cpe;
      ex = __builtin_amdgcn_exp2f(x);
      r = __builtin_amdgcn_rcpf(ex + 1.0f);
      acc0 = fmaf(vs[u], r, acc0);
      x = cp.y + cpe;
      ex = __builtin_amdgcn_exp2f(x);
      r = __builtin_amdgcn_rcpf(ex + 1.0f);
      acc1 = fmaf(vs[u], r, acc1);
      x = cp.z + cpe;
      ex = __builtin_amdgcn_exp2f(x);
      r = __builtin_amdgcn_rcpf(ex + 1.0f);
      acc2 = fmaf(vs[u], r, acc2);
      x = cp.w + cpe;
      ex = __builtin_amdgcn_exp2f(x);
      r = __builtin_amdgcn_rcpf(ex + 1.0f);
      acc3 = fmaf(vs[u], r, acc3);
    }
  }

  const long base = ((long)(b * DEC_LEN + d0) * ENC_LEN) + e;
  out[base + 0 * ENC_LEN] = acc0;
  out[base + 1 * ENC_LEN] = acc1;
  out[base + 2 * ENC_LEN] = acc2;
  out[base + 3 * ENC_LEN] = acc3;
}

// ---------------------------------------------------------------------------
// Masked softmax in place over e (1024) per row (b,d). Identical to
// softmax -> *mask -> renorm of the reference (shift/scale cancel).
// Grid: 1024 rows, 256 threads, 4 e per thread.
// ---------------------------------------------------------------------------
__global__ __launch_bounds__(256) void softmax_k(float* __restrict__ attn,
                                                 const float* __restrict__ mask) {
  const int row = blockIdx.x;
  const int b = row >> 8;  // DEC_LEN = 256
  const int tid = threadIdx.x;
  float* rp = attn + (long)row * ENC_LEN;
  const float* mp = mask + b * ENC_LEN;

  float l[4], m[4];
#pragma unroll
  for (int j = 0; j < 4; ++j) {
    l[j] = rp[tid + 256 * j];
    m[j] = mp[tid + 256 * j];
  }

  __shared__ float redmax[4];
  __shared__ float redsum[4];
  const int lane = tid & 63;
  const int wid = tid >> 6;

  float tm = fmaxf(fmaxf(l[0], l[1]), fmaxf(l[2], l[3]));
#pragma unroll
  for (int off = 1; off < 64; off <<= 1) tm = fmaxf(tm, __shfl_xor(tm, off, 64));
  if (lane == 0) redmax[wid] = tm;
  __syncthreads();
  const float rmax = fmaxf(fmaxf(redmax[0], redmax[1]), fmaxf(redmax[2], redmax[3]));

  const float LOG2E = 1.4426950408889634f;
  float p[4];
  float ts = 0.f;
#pragma unroll
  for (int j = 0; j < 4; ++j) {
    p[j] = __builtin_amdgcn_exp2f((l[j] - rmax) * LOG2E) * m[j];
    ts += p[j];
  }
#pragma unroll
  for (int off = 1; off < 64; off <<= 1) ts += __shfl_xor(ts, off, 64);
  if (lane == 0) redsum[wid] = ts;
  __syncthreads();
  const float rsum = redsum[0] + redsum[1] + redsum[2] + redsum[3];

  const float inv = 1.0f / rsum;
#pragma unroll
  for (int j = 0; j < 4; ++j) rp[tid + 256 * j] = p[j] * inv;
}

// ---------------------------------------------------------------------------
extern "C" void kernel_launch(void* const* d_in, const int* in_sizes, int n_in,
                              void* d_out, int out_size, void* d_ws, size_t ws_size,
                              hipStream_t stream) {
  const float* enc = (const float*)d_in[0];   // [4,1024,1024]
  const float* dec = (const float*)d_in[1];   // [4,256,1024]
  const float* mask = (const float*)d_in[2];  // [4,1024]
  const float* Wh = (const float*)d_in[3];    // [1024,256]
  const float* Ws = (const float*)d_in[4];    // [1024,256]
  const float* bs = (const float*)d_in[5];    // [256]
  const float* v = (const float*)d_in[6];     // [256]

  float* ctx = (float*)d_out;                       // [4,256,1024]
  float* attn = ctx + (long)BB * DEC_LEN * ENC_H;   // [4,256,1024] logits->attn

  float* pd = (float*)d_ws;                       // [4,256,256]
  float* peT = pd + (long)BB * DEC_LEN * ATTN_A;  // [4,256a,1024e]

  // 1) proj_dec = dec @ Ws + bs  (collapsed M = 4*256 = 1024)
  gemm64<0, true><<<dim3(ATTN_A / 64, (BB * DEC_LEN) / 64, 1), 256, 0, stream>>>(
      dec, Ws, bs, pd, ENC_H, ENC_H, ATTN_A, ATTN_A, 0, 0, 0);

  // 2) proj_enc^T: (enc @ Wh) stored as peT[b][a][e]  (collapsed M = 4096)
  gemm64<1, false><<<dim3(ATTN_A / 64, (BB * ENC_LEN) / 64, 1), 256, 0, stream>>>(
      enc, Wh, nullptr, peT, ENC_H, ENC_H, ATTN_A, 0, 0, 0, 0);

  // 3) logits into attn region of d_out
  logits_k<<<dim3(ENC_LEN / 256, DEC_LEN / 4, BB), 256, 0, stream>>>(peT, pd, v, attn);

  // 4) masked softmax in place
  softmax_k<<<dim3(BB * DEC_LEN, 1, 1), 256, 0, stream>>>(attn, mask);

  // 5) context = attn @ enc  (per-batch GEMM, M=256, N=1024, K=1024)
  gemm64<0, false><<<dim3(ENC_H / 64, DEC_LEN / 64, BB), 256, 0, stream>>>(
      attn, enc, nullptr, ctx, ENC_LEN, ENC_LEN, ENC_H, ENC_H,
      (long)DEC_LEN * ENC_LEN, (long)ENC_LEN * ENC_H, (long)DEC_LEN * ENC_H);
}

// Round 3
// 220.941 us; speedup vs baseline: 1.3870x; 1.3870x over previous
//
#include <hip/hip_runtime.h>
#include <hip/hip_bf16.h>

// Problem dims (fixed by reference)
#define BB 4
#define ENC_LEN 1024
#define DEC_LEN 256
#define ENC_H 1024
#define ATTN_A 256

typedef short bf16x8 __attribute__((ext_vector_type(8)));
typedef float f32x4 __attribute__((ext_vector_type(4)));
typedef unsigned int u32x2 __attribute__((ext_vector_type(2)));

union F4U {
  float4 v;
  float f[4];
};
union Q2D {
  uint4 q;
  u32x2 d[2];
};
union BF8 {
  u32x2 d[2];
  bf16x8 v;
};

// fp32 -> bf16 round-to-nearest-even
static __device__ __forceinline__ unsigned short f2bf(float x) {
  union {
    float f;
    unsigned int u;
  } c;
  c.f = x;
  unsigned int r = c.u + 0x7FFFu + ((c.u >> 16) & 1u);
  return (unsigned short)(r >> 16);
}

// ---------------------------------------------------------------------------
// Transpose + convert: in f32 [R][C] -> out bf16 [C][R]. 64x64 tiles.
// grid (C/64, R/64, batch). All LDS accesses <= 8B-aligned-safe.
// ---------------------------------------------------------------------------
__global__ __launch_bounds__(256) void transpose_cvt(const float* __restrict__ in,
                                                     unsigned short* __restrict__ out,
                                                     int R, int C, long inStride,
                                                     long outStride) {
  __shared__ unsigned short T[64][68];  // 136B rows (mult of 8) — ushort4 ok
  const int b = blockIdx.z;
  in += (long)b * inStride;
  out += (long)b * outStride;
  const int r0 = blockIdx.y * 64;
  const int c0 = blockIdx.x * 64;
  const int t = threadIdx.x;
  const int lr = t >> 4;         // 0..15
  const int lc4 = (t & 15) * 4;  // 0..60

#pragma unroll
  for (int p = 0; p < 4; ++p) {
    const int r = lr + p * 16;
    const float4 v = *(const float4*)&in[(long)(r0 + r) * C + c0 + lc4];
    ushort4 o;
    o.x = f2bf(v.x);
    o.y = f2bf(v.y);
    o.z = f2bf(v.z);
    o.w = f2bf(v.w);
    *(ushort4*)&T[r][lc4] = o;  // addr = r*136 + lc4*2, 8B aligned
  }
  __syncthreads();
#pragma unroll
  for (int p = 0; p < 4; ++p) {
    const int c = lr + p * 16;  // output row = input col
    ushort4 o;
    o.x = T[lc4 + 0][c];
    o.y = T[lc4 + 1][c];
    o.z = T[lc4 + 2][c];
    o.w = T[lc4 + 3][c];
    *(ushort4*)&out[(long)(c0 + c) * R + r0 + lc4] = o;
  }
}

// ---------------------------------------------------------------------------
// bf16 MFMA GEMM: C(MxN, f32) = A(MxK, f32, cvt on the fly) * BT^T
// BT bf16 [N][K]. Tile 64x64, BK=32, 4 waves, wave = 32x32 = 2x2 mfma 16x16x32.
// LDS rows stride 36 ushorts (72B): all accesses b64-aligned; fragment b64
// reads are bank-balanced (start dword = l16*18+quad*4 covers evens uniformly).
// OMODE 0: C[row*ldc+col] (+bias). OMODE 1: rows collapsed (b*1024+e),
//          write C[b][col][e] via LDS-transposed epilogue.
// ---------------------------------------------------------------------------
template <int OMODE, bool BIAS>
__global__ __launch_bounds__(256) void mgemm(const float* __restrict__ A,
                                             const unsigned short* __restrict__ BT,
                                             const float* __restrict__ bias,
                                             float* __restrict__ C, int K, int lda,
                                             int ldc, long sA, long sBT, long sC) {
  const int bz = blockIdx.z;
  A += (long)bz * sA;
  BT += (long)bz * sBT;
  C += (long)bz * sC;

  __shared__ unsigned short As[64][36];  // [m][k]
  __shared__ unsigned short Bs[64][36];  // [n][k]

  const int tid = threadIdx.x;
  const int lane = tid & 63;
  const int wave = tid >> 6;
  const int quad = lane >> 4;
  const int l16 = lane & 15;
  const int wm = (wave >> 1) * 32;
  const int wn = (wave & 1) * 32;

  const int m0 = blockIdx.y * 64;
  const int n0 = blockIdx.x * 64;

  // staging map: row = tid>>2 (0..63), k-chunk = (tid&3)*8
  const int sr = tid >> 2;
  const int sk = (tid & 3) * 8;

  f32x4 acc[2][2] = {{{0.f, 0.f, 0.f, 0.f}, {0.f, 0.f, 0.f, 0.f}},
                     {{0.f, 0.f, 0.f, 0.f}, {0.f, 0.f, 0.f, 0.f}}};

  const float* Ap = A + (long)(m0 + sr) * lda + sk;
  const unsigned short* Bp = BT + (long)(n0 + sr) * K + sk;

  for (int k0 = 0; k0 < K; k0 += 32) {
    F4U a0, a1;
    a0.v = *(const float4*)(Ap + k0);
    a1.v = *(const float4*)(Ap + k0 + 4);
    Q2D bv;
    bv.q = *(const uint4*)(Bp + k0);
    __syncthreads();  // previous tile fully consumed
    Q2D av;
    av.q.x = (unsigned int)f2bf(a0.f[0]) | ((unsigned int)f2bf(a0.f[1]) << 16);
    av.q.y = (unsigned int)f2bf(a0.f[2]) | ((unsigned int)f2bf(a0.f[3]) << 16);
    av.q.z = (unsigned int)f2bf(a1.f[0]) | ((unsigned int)f2bf(a1.f[1]) << 16);
    av.q.w = (unsigned int)f2bf(a1.f[2]) | ((unsigned int)f2bf(a1.f[3]) << 16);
    *(u32x2*)&As[sr][sk] = av.d[0];      // 72*sr + 2*sk : 8B aligned
    *(u32x2*)&As[sr][sk + 4] = av.d[1];
    *(u32x2*)&Bs[sr][sk] = bv.d[0];
    *(u32x2*)&Bs[sr][sk + 4] = bv.d[1];
    __syncthreads();

    bf16x8 af[2], bfr[2];
#pragma unroll
    for (int i = 0; i < 2; ++i) {
      BF8 t;
      t.d[0] = *(const u32x2*)&As[wm + i * 16 + l16][quad * 8];
      t.d[1] = *(const u32x2*)&As[wm + i * 16 + l16][quad * 8 + 4];
      af[i] = t.v;
    }
#pragma unroll
    for (int j = 0; j < 2; ++j) {
      BF8 t;
      t.d[0] = *(const u32x2*)&Bs[wn + j * 16 + l16][quad * 8];
      t.d[1] = *(const u32x2*)&Bs[wn + j * 16 + l16][quad * 8 + 4];
      bfr[j] = t.v;
    }
#pragma unroll
    for (int i = 0; i < 2; ++i)
#pragma unroll
      for (int j = 0; j < 2; ++j)
        acc[i][j] = __builtin_amdgcn_mfma_f32_16x16x32_bf16(af[i], bfr[j], acc[i][j],
                                                            0, 0, 0);
  }

  if constexpr (OMODE == 0) {
#pragma unroll
    for (int j = 0; j < 2; ++j) {
      const int col = n0 + wn + j * 16 + l16;
      const float bj = BIAS ? bias[col] : 0.f;
#pragma unroll
      for (int i = 0; i < 2; ++i) {
        const int row = m0 + wm + i * 16 + quad * 4;
#pragma unroll
        for (int r = 0; r < 4; ++r)
          C[(long)(row + r) * ldc + col] = acc[i][j][r] + bj;
      }
    }
  } else {
    // collapsed rows m = b*1024 + e; write C[b][col][e] coalesced via LDS
    __shared__ float Cs[64][68];  // 272B rows (mult of 16) — float4 ok
    __syncthreads();
#pragma unroll
    for (int i = 0; i < 2; ++i)
#pragma unroll
      for (int j = 0; j < 2; ++j)
#pragma unroll
        for (int r = 0; r < 4; ++r)
          Cs[wn + j * 16 + l16][wm + i * 16 + quad * 4 + r] = acc[i][j][r];
    __syncthreads();
    const int gb = m0 >> 10;
    const int e0 = m0 & 1023;
#pragma unroll
    for (int p = 0; p < 4; ++p) {
      const int arow = (tid >> 4) + p * 16;
      const int e4 = (tid & 15) * 4;
      const float4 o = *(const float4*)&Cs[arow][e4];
      *(float4*)&C[(long)gb * (ATTN_A * ENC_LEN) + (long)(n0 + arow) * ENC_LEN + e0 +
                   e4] = o;
    }
  }
}

// ---------------------------------------------------------------------------
// Fallback fp32 GEMM (proven Round-1 path, used only if ws_size < 8MB)
// ---------------------------------------------------------------------------
template <int OMODE, bool BIAS>
__global__ __launch_bounds__(256) void gemm64(const float* __restrict__ A,
                                              const float* __restrict__ B,
                                              const float* __restrict__ bias,
                                              float* __restrict__ C,
                                              int K, int lda, int ldb, int ldc,
                                              long sA, long sB, long sC) {
  const int bz = blockIdx.z;
  A += (long)bz * sA;
  B += (long)bz * sB;
  C += (long)bz * sC;

  const int tid = threadIdx.x;
  const int tx = tid & 15;
  const int ty = tid >> 4;

  __shared__ float As2[16][64];
  __shared__ float Bs2[16][64];

  float acc[4][4];
#pragma unroll
  for (int i = 0; i < 4; ++i)
#pragma unroll
    for (int j = 0; j < 4; ++j) acc[i][j] = 0.f;

  const int ar = tid >> 2;
  const int ak4 = (tid & 3) << 2;
  const int br = tid >> 4;
  const int bn4 = (tid & 15) << 2;

  const float* Aload = A + (long)(blockIdx.y * 64 + ar) * lda + ak4;
  const float* Bload = B + (long)br * ldb + blockIdx.x * 64 + bn4;

  for (int k0 = 0; k0 < K; k0 += 16) {
    const float4 av = *(const float4*)(Aload + k0);
    const float4 bv = *(const float4*)(Bload + (long)k0 * ldb);
    __syncthreads();
    As2[ak4 + 0][ar] = av.x;
    As2[ak4 + 1][ar] = av.y;
    As2[ak4 + 2][ar] = av.z;
    As2[ak4 + 3][ar] = av.w;
    *(float4*)&Bs2[br][bn4] = bv;
    __syncthreads();
#pragma unroll
    for (int kk = 0; kk < 16; ++kk) {
      const float4 a4 = *(const float4*)&As2[kk][ty << 2];
      const float4 b4 = *(const float4*)&Bs2[kk][tx << 2];
      const float am[4] = {a4.x, a4.y, a4.z, a4.w};
      const float bn[4] = {b4.x, b4.y, b4.z, b4.w};
#pragma unroll
      for (int i = 0; i < 4; ++i)
#pragma unroll
        for (int j = 0; j < 4; ++j) acc[i][j] = fmaf(am[i], bn[j], acc[i][j]);
    }
  }

  if (OMODE == 0) {
    const int row0 = blockIdx.y * 64 + (ty << 2);
    const int col0 = blockIdx.x * 64 + (tx << 2);
    float4 bb4 = make_float4(0.f, 0.f, 0.f, 0.f);
    if (BIAS) bb4 = *(const float4*)&bias[col0];
#pragma unroll
    for (int i = 0; i < 4; ++i) {
      float4 o;
      o.x = acc[i][0] + bb4.x;
      o.y = acc[i][1] + bb4.y;
      o.z = acc[i][2] + bb4.z;
      o.w = acc[i][3] + bb4.w;
      *(float4*)&C[(long)(row0 + i) * ldc + col0] = o;
    }
  } else {
#pragma unroll
    for (int i = 0; i < 4; ++i) {
      const int gr = blockIdx.y * 64 + (ty << 2) + i;
      const int b = gr >> 10;
      const int e = gr & 1023;
#pragma unroll
      for (int j = 0; j < 4; ++j) {
        const int col = blockIdx.x * 64 + (tx << 2) + j;
        C[(long)b * (ATTN_A * ENC_LEN) + (long)col * ENC_LEN + e] = acc[i][j];
      }
    }
  }
}

// ---------------------------------------------------------------------------
// Logits: acc = sum_a -2*v[a]*rcp(exp2(C2*(pd+pe))+1)  (== v·tanh + const)
// Thread = one e, EIGHT d's. Grid (ENC/256, DEC/8, B).
// ---------------------------------------------------------------------------
__global__ __launch_bounds__(256) void logits_k(const float* __restrict__ peT,
                                                const float* __restrict__ pd,
                                                const float* __restrict__ v,
                                                float* __restrict__ out) {
  const int tid = threadIdx.x;
  const int e = blockIdx.x * 256 + tid;
  const int d0 = blockIdx.y * 8;
  const int b = blockIdx.z;

  const float C2 = 2.8853900817779268f;  // 2*log2(e)

  __shared__ float cpd[ATTN_A][8];
  __shared__ float vv[ATTN_A];

  {
    const int a = tid;
#pragma unroll
    for (int dd = 0; dd < 8; ++dd)
      cpd[a][dd] = C2 * pd[((b * DEC_LEN + d0 + dd) * ATTN_A) + a];
    vv[a] = -2.0f * v[a];
  }
  __syncthreads();

  float acc[8] = {0.f, 0.f, 0.f, 0.f, 0.f, 0.f, 0.f, 0.f};
  const float* pe = peT + (long)b * (ATTN_A * ENC_LEN) + e;

  for (int a = 0; a < ATTN_A; a += 4) {
    float pes[4];
#pragma unroll
    for (int u = 0; u < 4; ++u) pes[u] = pe[(long)(a + u) * ENC_LEN];
#pragma unroll
    for (int u = 0; u < 4; ++u) {
      const float cpe = C2 * pes[u];
      const float vu = vv[a + u];
      const float4 c0 = *(const float4*)&cpd[a + u][0];
      const float4 c1 = *(const float4*)&cpd[a + u][4];
      const float cd[8] = {c0.x, c0.y, c0.z, c0.w, c1.x, c1.y, c1.z, c1.w};
#pragma unroll
      for (int dd = 0; dd < 8; ++dd) {
        const float x = cd[dd] + cpe;
        const float ex = __builtin_amdgcn_exp2f(x);
        const float r = __builtin_amdgcn_rcpf(ex + 1.0f);
        acc[dd] = fmaf(vu, r, acc[dd]);
      }
    }
  }

  const long base = ((long)(b * DEC_LEN + d0) * ENC_LEN) + e;
#pragma unroll
  for (int dd = 0; dd < 8; ++dd) out[base + (long)dd * ENC_LEN] = acc[dd];
}

// ---------------------------------------------------------------------------
// Masked softmax in place over e (1024) per row (b,d). Grid: B*DEC rows.
// ---------------------------------------------------------------------------
__global__ __launch_bounds__(256) void softmax_k(float* __restrict__ attn,
                                                 const float* __restrict__ mask) {
  const int row = blockIdx.x;
  const int b = row >> 8;  // DEC_LEN = 256
  const int tid = threadIdx.x;
  float* rp = attn + (long)row * ENC_LEN;
  const float* mp = mask + b * ENC_LEN;

  float l[4], m[4];
#pragma unroll
  for (int j = 0; j < 4; ++j) {
    l[j] = rp[tid + 256 * j];
    m[j] = mp[tid + 256 * j];
  }

  __shared__ float redmax[4];
  __shared__ float redsum[4];
  const int lane = tid & 63;
  const int wid = tid >> 6;

  float tm = fmaxf(fmaxf(l[0], l[1]), fmaxf(l[2], l[3]));
#pragma unroll
  for (int off = 1; off < 64; off <<= 1) tm = fmaxf(tm, __shfl_xor(tm, off, 64));
  if (lane == 0) redmax[wid] = tm;
  __syncthreads();
  const float rmax = fmaxf(fmaxf(redmax[0], redmax[1]), fmaxf(redmax[2], redmax[3]));

  const float LOG2E = 1.4426950408889634f;
  float p[4];
  float ts = 0.f;
#pragma unroll
  for (int j = 0; j < 4; ++j) {
    p[j] = __builtin_amdgcn_exp2f((l[j] - rmax) * LOG2E) * m[j];
    ts += p[j];
  }
#pragma unroll
  for (int off = 1; off < 64; off <<= 1) ts += __shfl_xor(ts, off, 64);
  if (lane == 0) redsum[wid] = ts;
  __syncthreads();
  const float rsum = redsum[0] + redsum[1] + redsum[2] + redsum[3];

  const float inv = 1.0f / rsum;
#pragma unroll
  for (int j = 0; j < 4; ++j) rp[tid + 256 * j] = p[j] * inv;
}

// ---------------------------------------------------------------------------
extern "C" void kernel_launch(void* const* d_in, const int* in_sizes, int n_in,
                              void* d_out, int out_size, void* d_ws, size_t ws_size,
                              hipStream_t stream) {
  const float* enc = (const float*)d_in[0];   // [4,1024,1024]
  const float* dec = (const float*)d_in[1];   // [4,256,1024]
  const float* mask = (const float*)d_in[2];  // [4,1024]
  const float* Wh = (const float*)d_in[3];    // [1024,256]
  const float* Ws = (const float*)d_in[4];    // [1024,256]
  const float* bs = (const float*)d_in[5];    // [256]
  const float* v = (const float*)d_in[6];     // [256]

  float* ctx = (float*)d_out;                      // [4,256,1024]
  float* attn = ctx + (long)BB * DEC_LEN * ENC_H;  // [4,256,1024]

  const size_t FAST_WS = (size_t)BB * ENC_H * ENC_LEN * 2;  // 8 MB (encT)

  if (ws_size >= FAST_WS) {
    // ---- fast path (bf16 MFMA GEMMs) ----
    // phase A: ws = [pd 1MB][peT 4MB ...]; WhT/WsT live in d_out ctx region
    // phase B (after logits): ws[0..8MB) = encT
    float* pd = (float*)d_ws;
    float* peT = pd + (long)BB * DEC_LEN * ATTN_A;
    unsigned short* encT = (unsigned short*)d_ws;
    unsigned short* WhT = (unsigned short*)ctx;           // 0.5 MB
    unsigned short* WsT = WhT + (long)ATTN_A * ENC_H;     // 0.5 MB

    transpose_cvt<<<dim3(ATTN_A / 64, ENC_H / 64, 1), 256, 0, stream>>>(
        Wh, WhT, ENC_H, ATTN_A, 0, 0);
    transpose_cvt<<<dim3(ATTN_A / 64, ENC_H / 64, 1), 256, 0, stream>>>(
        Ws, WsT, ENC_H, ATTN_A, 0, 0);

    // pd = dec @ Ws + bs   (M = 4*256 collapsed)
    mgemm<0, true><<<dim3(ATTN_A / 64, (BB * DEC_LEN) / 64, 1), 256, 0, stream>>>(
        dec, WsT, bs, pd, ENC_H, ENC_H, ATTN_A, 0, 0, 0);

    // peT[b][a][e] = (enc @ Wh)^T   (M = 4*1024 collapsed)
    mgemm<1, false><<<dim3(ATTN_A / 64, (BB * ENC_LEN) / 64, 1), 256, 0, stream>>>(
        enc, WhT, nullptr, peT, ENC_H, ENC_H, 0, 0, 0, 0);

    logits_k<<<dim3(ENC_LEN / 256, DEC_LEN / 8, BB), 256, 0, stream>>>(peT, pd, v,
                                                                       attn);
    softmax_k<<<dim3(BB * DEC_LEN, 1, 1), 256, 0, stream>>>(attn, mask);

    // encT[b][h][e] (overwrites pd/peT — both dead now)
    transpose_cvt<<<dim3(ENC_H / 64, ENC_LEN / 64, BB), 256, 0, stream>>>(
        enc, encT, ENC_LEN, ENC_H, (long)ENC_LEN * ENC_H, (long)ENC_H * ENC_LEN);

    // ctx = attn @ enc   (per-batch; overwrites WhT/WsT — dead)
    mgemm<0, false><<<dim3(ENC_H / 64, DEC_LEN / 64, BB), 256, 0, stream>>>(
        attn, encT, nullptr, ctx, ENC_LEN, ENC_LEN, ENC_H, (long)DEC_LEN * ENC_LEN,
        (long)ENC_H * ENC_LEN, (long)DEC_LEN * ENC_H);
  } else {
    // ---- fallback (proven Round-1 fp32 path, 5 MB ws) ----
    float* pd = (float*)d_ws;
    float* peT = pd + (long)BB * DEC_LEN * ATTN_A;

    gemm64<0, true><<<dim3(ATTN_A / 64, (BB * DEC_LEN) / 64, 1), 256, 0, stream>>>(
        dec, Ws, bs, pd, ENC_H, ENC_H, ATTN_A, ATTN_A, 0, 0, 0);
    gemm64<1, false><<<dim3(ATTN_A / 64, (BB * ENC_LEN) / 64, 1), 256, 0, stream>>>(
        enc, Wh, nullptr, peT, ENC_H, ENC_H, ATTN_A, 0, 0, 0, 0);
    logits_k<<<dim3(ENC_LEN / 256, DEC_LEN / 8, BB), 256, 0, stream>>>(peT, pd, v,
                                                                       attn);
    softmax_k<<<dim3(BB * DEC_LEN, 1, 1), 256, 0, stream>>>(attn, mask);
    gemm64<0, false><<<dim3(ENC_H / 64, DEC_LEN / 64, BB), 256, 0, stream>>>(
        attn, enc, nullptr, ctx, ENC_LEN, ENC_LEN, ENC_H, ENC_H,
        (long)DEC_LEN * ENC_LEN, (long)ENC_LEN * ENC_H, (long)DEC_LEN * ENC_H);
  }
}

// Round 4
// 169.350 us; speedup vs baseline: 1.8096x; 1.3046x over previous
//
#include <hip/hip_runtime.h>
#include <hip/hip_bf16.h>

// Problem dims (fixed by reference)
#define BB 4
#define ENC_LEN 1024
#define DEC_LEN 256
#define ENC_H 1024
#define ATTN_A 256

#define C2F 2.8853900817779268f  // 2*log2(e)

typedef short bf16x8 __attribute__((ext_vector_type(8)));
typedef float f32x4 __attribute__((ext_vector_type(4)));
typedef unsigned int u32x2 __attribute__((ext_vector_type(2)));

union F4U {
  float4 v;
  float f[4];
};
union Q2D {
  uint4 q;
  u32x2 d[2];
};
union BF8 {
  u32x2 d[2];
  bf16x8 v;
};

// fp32 -> bf16 round-to-nearest-even
static __device__ __forceinline__ unsigned short f2bf(float x) {
  union {
    float f;
    unsigned int u;
  } c;
  c.f = x;
  unsigned int r = c.u + 0x7FFFu + ((c.u >> 16) & 1u);
  return (unsigned short)(r >> 16);
}

// ---------------------------------------------------------------------------
// Transpose + convert: in f32 [R][C] -> out bf16 [C][R]. 64x64 tiles.
// ---------------------------------------------------------------------------
__global__ __launch_bounds__(256) void transpose_cvt(const float* __restrict__ in,
                                                     unsigned short* __restrict__ out,
                                                     int R, int C, long inStride,
                                                     long outStride) {
  __shared__ unsigned short T[64][68];
  const int b = blockIdx.z;
  in += (long)b * inStride;
  out += (long)b * outStride;
  const int r0 = blockIdx.y * 64;
  const int c0 = blockIdx.x * 64;
  const int t = threadIdx.x;
  const int lr = t >> 4;
  const int lc4 = (t & 15) * 4;

#pragma unroll
  for (int p = 0; p < 4; ++p) {
    const int r = lr + p * 16;
    const float4 v = *(const float4*)&in[(long)(r0 + r) * C + c0 + lc4];
    ushort4 o;
    o.x = f2bf(v.x);
    o.y = f2bf(v.y);
    o.z = f2bf(v.z);
    o.w = f2bf(v.w);
    *(ushort4*)&T[r][lc4] = o;
  }
  __syncthreads();
#pragma unroll
  for (int p = 0; p < 4; ++p) {
    const int c = lr + p * 16;
    ushort4 o;
    o.x = T[lc4 + 0][c];
    o.y = T[lc4 + 1][c];
    o.z = T[lc4 + 2][c];
    o.w = T[lc4 + 3][c];
    *(ushort4*)&out[(long)(c0 + c) * R + r0 + lc4] = o;
  }
}

// Both weight transposes in one dispatch (z selects Wh or Ws). [1024][256]->[256][1024]
__global__ __launch_bounds__(256) void transpose_w2(const float* __restrict__ w0,
                                                    const float* __restrict__ w1,
                                                    unsigned short* __restrict__ o0,
                                                    unsigned short* __restrict__ o1) {
  __shared__ unsigned short T[64][68];
  const float* in = blockIdx.z ? w1 : w0;
  unsigned short* out = blockIdx.z ? o1 : o0;
  const int r0 = blockIdx.y * 64;
  const int c0 = blockIdx.x * 64;
  const int t = threadIdx.x;
  const int lr = t >> 4;
  const int lc4 = (t & 15) * 4;

#pragma unroll
  for (int p = 0; p < 4; ++p) {
    const int r = lr + p * 16;
    const float4 v = *(const float4*)&in[(long)(r0 + r) * ATTN_A + c0 + lc4];
    ushort4 o;
    o.x = f2bf(v.x);
    o.y = f2bf(v.y);
    o.z = f2bf(v.z);
    o.w = f2bf(v.w);
    *(ushort4*)&T[r][lc4] = o;
  }
  __syncthreads();
#pragma unroll
  for (int p = 0; p < 4; ++p) {
    const int c = lr + p * 16;
    ushort4 o;
    o.x = T[lc4 + 0][c];
    o.y = T[lc4 + 1][c];
    o.z = T[lc4 + 2][c];
    o.w = T[lc4 + 3][c];
    *(ushort4*)&out[(long)(c0 + c) * ENC_H + r0 + lc4] = o;
  }
}

// ---------------------------------------------------------------------------
// Fused projection GEMM (one dispatch): grid (4, 80).
//  y <  16: pdE[m][a]  = exp2(C2*(dec·Ws + bs))   (M=1024 collapsed b,d)
//  y >= 16: peT[b][a][e] = C2*(enc·Wh)            (M=4096 collapsed b,e; LDS
//           transposed epilogue)
// Tile 64x64, BK=32, 4 waves, wave = 32x32 = 2x2 mfma_f32_16x16x32_bf16.
// LDS rows stride 36 ushorts (72B): b64-aligned, bank-balanced.
// ---------------------------------------------------------------------------
__global__ __launch_bounds__(256) void proj_gemm(const float* __restrict__ dec,
                                                 const float* __restrict__ enc,
                                                 const unsigned short* __restrict__ WsT,
                                                 const unsigned short* __restrict__ WhT,
                                                 const float* __restrict__ bs,
                                                 float* __restrict__ pdE,
                                                 float* __restrict__ peT) {
  __shared__ unsigned short As[64][36];
  __shared__ unsigned short Bs[64][36];
  __shared__ float Cs[64][68];

  const bool isPD = blockIdx.y < 16;
  const float* A = isPD ? dec : enc;
  const unsigned short* BT = isPD ? WsT : WhT;
  const int m0 = (isPD ? blockIdx.y : (blockIdx.y - 16)) * 64;
  const int n0 = blockIdx.x * 64;

  const int tid = threadIdx.x;
  const int lane = tid & 63;
  const int wave = tid >> 6;
  const int quad = lane >> 4;
  const int l16 = lane & 15;
  const int wm = (wave >> 1) * 32;
  const int wn = (wave & 1) * 32;

  const int sr = tid >> 2;
  const int sk = (tid & 3) * 8;

  f32x4 acc[2][2] = {{{0.f, 0.f, 0.f, 0.f}, {0.f, 0.f, 0.f, 0.f}},
                     {{0.f, 0.f, 0.f, 0.f}, {0.f, 0.f, 0.f, 0.f}}};

  const float* Ap = A + (long)(m0 + sr) * ENC_H + sk;
  const unsigned short* Bp = BT + (long)(n0 + sr) * ENC_H + sk;

  for (int k0 = 0; k0 < ENC_H; k0 += 32) {
    F4U a0, a1;
    a0.v = *(const float4*)(Ap + k0);
    a1.v = *(const float4*)(Ap + k0 + 4);
    Q2D bv;
    bv.q = *(const uint4*)(Bp + k0);
    __syncthreads();
    Q2D av;
    av.q.x = (unsigned int)f2bf(a0.f[0]) | ((unsigned int)f2bf(a0.f[1]) << 16);
    av.q.y = (unsigned int)f2bf(a0.f[2]) | ((unsigned int)f2bf(a0.f[3]) << 16);
    av.q.z = (unsigned int)f2bf(a1.f[0]) | ((unsigned int)f2bf(a1.f[1]) << 16);
    av.q.w = (unsigned int)f2bf(a1.f[2]) | ((unsigned int)f2bf(a1.f[3]) << 16);
    *(u32x2*)&As[sr][sk] = av.d[0];
    *(u32x2*)&As[sr][sk + 4] = av.d[1];
    *(u32x2*)&Bs[sr][sk] = bv.d[0];
    *(u32x2*)&Bs[sr][sk + 4] = bv.d[1];
    __syncthreads();

    bf16x8 af[2], bfr[2];
#pragma unroll
    for (int i = 0; i < 2; ++i) {
      BF8 t;
      t.d[0] = *(const u32x2*)&As[wm + i * 16 + l16][quad * 8];
      t.d[1] = *(const u32x2*)&As[wm + i * 16 + l16][quad * 8 + 4];
      af[i] = t.v;
    }
#pragma unroll
    for (int j = 0; j < 2; ++j) {
      BF8 t;
      t.d[0] = *(const u32x2*)&Bs[wn + j * 16 + l16][quad * 8];
      t.d[1] = *(const u32x2*)&Bs[wn + j * 16 + l16][quad * 8 + 4];
      bfr[j] = t.v;
    }
#pragma unroll
    for (int i = 0; i < 2; ++i)
#pragma unroll
      for (int j = 0; j < 2; ++j)
        acc[i][j] = __builtin_amdgcn_mfma_f32_16x16x32_bf16(af[i], bfr[j], acc[i][j],
                                                            0, 0, 0);
  }

  if (isPD) {
    // pdE[m][a] = exp2(C2*(acc + bias))
#pragma unroll
    for (int j = 0; j < 2; ++j) {
      const int col = n0 + wn + j * 16 + l16;
      const float bj = bs[col];
#pragma unroll
      for (int i = 0; i < 2; ++i) {
        const int row = m0 + wm + i * 16 + quad * 4;
#pragma unroll
        for (int r = 0; r < 4; ++r)
          pdE[(long)(row + r) * ATTN_A + col] =
              __builtin_amdgcn_exp2f(C2F * (acc[i][j][r] + bj));
      }
    }
  } else {
    // peT[b][a][e] = C2*acc, via LDS transpose for coalesced e-writes
    __syncthreads();
#pragma unroll
    for (int i = 0; i < 2; ++i)
#pragma unroll
      for (int j = 0; j < 2; ++j)
#pragma unroll
        for (int r = 0; r < 4; ++r)
          Cs[wn + j * 16 + l16][wm + i * 16 + quad * 4 + r] = C2F * acc[i][j][r];
    __syncthreads();
    const int gb = m0 >> 10;
    const int e0 = m0 & 1023;
#pragma unroll
    for (int p = 0; p < 4; ++p) {
      const int arow = (tid >> 4) + p * 16;
      const int e4 = (tid & 15) * 4;
      const float4 o = *(const float4*)&Cs[arow][e4];
      *(float4*)&peT[(long)gb * (ATTN_A * ENC_LEN) + (long)(n0 + arow) * ENC_LEN +
                     e0 + e4] = o;
    }
  }
}

// ---------------------------------------------------------------------------
// ctx GEMM: C = A(fp32, cvt) * BT^T, plain epilogue. Same tile as proj_gemm.
// ---------------------------------------------------------------------------
__global__ __launch_bounds__(256) void ctx_gemm(const float* __restrict__ A,
                                                const unsigned short* __restrict__ BT,
                                                float* __restrict__ C, int K, int lda,
                                                int ldc, long sA, long sBT, long sC) {
  const int bz = blockIdx.z;
  A += (long)bz * sA;
  BT += (long)bz * sBT;
  C += (long)bz * sC;

  __shared__ unsigned short As[64][36];
  __shared__ unsigned short Bs[64][36];

  const int tid = threadIdx.x;
  const int lane = tid & 63;
  const int wave = tid >> 6;
  const int quad = lane >> 4;
  const int l16 = lane & 15;
  const int wm = (wave >> 1) * 32;
  const int wn = (wave & 1) * 32;

  const int m0 = blockIdx.y * 64;
  const int n0 = blockIdx.x * 64;
  const int sr = tid >> 2;
  const int sk = (tid & 3) * 8;

  f32x4 acc[2][2] = {{{0.f, 0.f, 0.f, 0.f}, {0.f, 0.f, 0.f, 0.f}},
                     {{0.f, 0.f, 0.f, 0.f}, {0.f, 0.f, 0.f, 0.f}}};

  const float* Ap = A + (long)(m0 + sr) * lda + sk;
  const unsigned short* Bp = BT + (long)(n0 + sr) * K + sk;

  for (int k0 = 0; k0 < K; k0 += 32) {
    F4U a0, a1;
    a0.v = *(const float4*)(Ap + k0);
    a1.v = *(const float4*)(Ap + k0 + 4);
    Q2D bv;
    bv.q = *(const uint4*)(Bp + k0);
    __syncthreads();
    Q2D av;
    av.q.x = (unsigned int)f2bf(a0.f[0]) | ((unsigned int)f2bf(a0.f[1]) << 16);
    av.q.y = (unsigned int)f2bf(a0.f[2]) | ((unsigned int)f2bf(a0.f[3]) << 16);
    av.q.z = (unsigned int)f2bf(a1.f[0]) | ((unsigned int)f2bf(a1.f[1]) << 16);
    av.q.w = (unsigned int)f2bf(a1.f[2]) | ((unsigned int)f2bf(a1.f[3]) << 16);
    *(u32x2*)&As[sr][sk] = av.d[0];
    *(u32x2*)&As[sr][sk + 4] = av.d[1];
    *(u32x2*)&Bs[sr][sk] = bv.d[0];
    *(u32x2*)&Bs[sr][sk + 4] = bv.d[1];
    __syncthreads();

    bf16x8 af[2], bfr[2];
#pragma unroll
    for (int i = 0; i < 2; ++i) {
      BF8 t;
      t.d[0] = *(const u32x2*)&As[wm + i * 16 + l16][quad * 8];
      t.d[1] = *(const u32x2*)&As[wm + i * 16 + l16][quad * 8 + 4];
      af[i] = t.v;
    }
#pragma unroll
    for (int j = 0; j < 2; ++j) {
      BF8 t;
      t.d[0] = *(const u32x2*)&Bs[wn + j * 16 + l16][quad * 8];
      t.d[1] = *(const u32x2*)&Bs[wn + j * 16 + l16][quad * 8 + 4];
      bfr[j] = t.v;
    }
#pragma unroll
    for (int i = 0; i < 2; ++i)
#pragma unroll
      for (int j = 0; j < 2; ++j)
        acc[i][j] = __builtin_amdgcn_mfma_f32_16x16x32_bf16(af[i], bfr[j], acc[i][j],
                                                            0, 0, 0);
  }

#pragma unroll
  for (int j = 0; j < 2; ++j) {
    const int col = n0 + wn + j * 16 + l16;
#pragma unroll
    for (int i = 0; i < 2; ++i) {
      const int row = m0 + wm + i * 16 + quad * 4;
#pragma unroll
      for (int r = 0; r < 4; ++r) C[(long)(row + r) * ldc + col] = acc[i][j][r];
    }
  }
}

// ---------------------------------------------------------------------------
// Logits (exp-factored): part = sum_{a in half} (-2 v_a) * rcp(Ed[d,a]*Ee[a,e] + 1)
// Ed = exp2(C2*pd) precomputed by proj_gemm; peT pre-scaled by C2.
// Grid (ENC/256, DEC/8, B*2): z = b*2 + ahalf. Each block: 128 a's, 8 d's, 256 e's.
// Partials to p0 (attn region) / p1 (ctx region); softmax sums them.
// ---------------------------------------------------------------------------
__global__ __launch_bounds__(256) void logits_k(const float* __restrict__ peT,
                                                const float* __restrict__ pdE,
                                                const float* __restrict__ v,
                                                float* __restrict__ p0,
                                                float* __restrict__ p1) {
  const int tid = threadIdx.x;
  const int e = blockIdx.x * 256 + tid;
  const int d0 = blockIdx.y * 8;
  const int b = blockIdx.z >> 1;
  const int a0 = (blockIdx.z & 1) * 128;

  __shared__ float Ed[128][8];
  __shared__ float vv[128];

  if (tid < 128) {
    const int a = tid;
#pragma unroll
    for (int dd = 0; dd < 8; ++dd)
      Ed[a][dd] = pdE[(long)(b * DEC_LEN + d0 + dd) * ATTN_A + a0 + a];
    vv[a] = -2.0f * v[a0 + a];
  }
  __syncthreads();

  float acc[8] = {0.f, 0.f, 0.f, 0.f, 0.f, 0.f, 0.f, 0.f};
  const float* pe = peT + (long)b * (ATTN_A * ENC_LEN) + (long)a0 * ENC_LEN + e;

  float pen[4];
#pragma unroll
  for (int u = 0; u < 4; ++u) pen[u] = pe[(long)u * ENC_LEN];

  for (int a4 = 0; a4 < 128; a4 += 4) {
    float pes[4];
#pragma unroll
    for (int u = 0; u < 4; ++u) pes[u] = pen[u];
    if (a4 + 4 < 128) {
#pragma unroll
      for (int u = 0; u < 4; ++u) pen[u] = pe[(long)(a4 + 4 + u) * ENC_LEN];
    }
#pragma unroll
    for (int u = 0; u < 4; ++u) {
      const float Ee = __builtin_amdgcn_exp2f(pes[u]);
      const float vu = vv[a4 + u];
      const float4 e0 = *(const float4*)&Ed[a4 + u][0];
      const float4 e1 = *(const float4*)&Ed[a4 + u][4];
      const float ed[8] = {e0.x, e0.y, e0.z, e0.w, e1.x, e1.y, e1.z, e1.w};
#pragma unroll
      for (int dd = 0; dd < 8; ++dd) {
        const float den = fmaf(ed[dd], Ee, 1.0f);
        const float r = __builtin_amdgcn_rcpf(den);
        acc[dd] = fmaf(vu, r, acc[dd]);
      }
    }
  }

  float* po = (blockIdx.z & 1) ? p1 : p0;
  const long base = ((long)(b * DEC_LEN + d0) * ENC_LEN) + e;
#pragma unroll
  for (int dd = 0; dd < 8; ++dd) po[base + (long)dd * ENC_LEN] = acc[dd];
}

// ---------------------------------------------------------------------------
// Masked softmax over e: logits = p0+p1; result written to p0 (attn).
// ---------------------------------------------------------------------------
__global__ __launch_bounds__(256) void softmax2_k(float* __restrict__ p0,
                                                  const float* __restrict__ p1,
                                                  const float* __restrict__ mask) {
  const int row = blockIdx.x;
  const int b = row >> 8;
  const int tid = threadIdx.x;
  float* rp = p0 + (long)row * ENC_LEN;
  const float* rq = p1 + (long)row * ENC_LEN;
  const float* mp = mask + b * ENC_LEN;

  float l[4], m[4];
#pragma unroll
  for (int j = 0; j < 4; ++j) {
    l[j] = rp[tid + 256 * j] + rq[tid + 256 * j];
    m[j] = mp[tid + 256 * j];
  }

  __shared__ float redmax[4];
  __shared__ float redsum[4];
  const int lane = tid & 63;
  const int wid = tid >> 6;

  float tm = fmaxf(fmaxf(l[0], l[1]), fmaxf(l[2], l[3]));
#pragma unroll
  for (int off = 1; off < 64; off <<= 1) tm = fmaxf(tm, __shfl_xor(tm, off, 64));
  if (lane == 0) redmax[wid] = tm;
  __syncthreads();
  const float rmax = fmaxf(fmaxf(redmax[0], redmax[1]), fmaxf(redmax[2], redmax[3]));

  const float LOG2E = 1.4426950408889634f;
  float p[4];
  float ts = 0.f;
#pragma unroll
  for (int j = 0; j < 4; ++j) {
    p[j] = __builtin_amdgcn_exp2f((l[j] - rmax) * LOG2E) * m[j];
    ts += p[j];
  }
#pragma unroll
  for (int off = 1; off < 64; off <<= 1) ts += __shfl_xor(ts, off, 64);
  if (lane == 0) redsum[wid] = ts;
  __syncthreads();
  const float rsum = redsum[0] + redsum[1] + redsum[2] + redsum[3];

  const float inv = 1.0f / rsum;
#pragma unroll
  for (int j = 0; j < 4; ++j) rp[tid + 256 * j] = p[j] * inv;
}

// ---------------------------------------------------------------------------
// Fallback path kernels (proven Round-1/3 fp32 versions, used if ws too small)
// ---------------------------------------------------------------------------
template <int OMODE, bool BIAS>
__global__ __launch_bounds__(256) void gemm64(const float* __restrict__ A,
                                              const float* __restrict__ B,
                                              const float* __restrict__ bias,
                                              float* __restrict__ C,
                                              int K, int lda, int ldb, int ldc,
                                              long sA, long sB, long sC) {
  const int bz = blockIdx.z;
  A += (long)bz * sA;
  B += (long)bz * sB;
  C += (long)bz * sC;

  const int tid = threadIdx.x;
  const int tx = tid & 15;
  const int ty = tid >> 4;

  __shared__ float As2[16][64];
  __shared__ float Bs2[16][64];

  float acc[4][4];
#pragma unroll
  for (int i = 0; i < 4; ++i)
#pragma unroll
    for (int j = 0; j < 4; ++j) acc[i][j] = 0.f;

  const int ar = tid >> 2;
  const int ak4 = (tid & 3) << 2;
  const int br = tid >> 4;
  const int bn4 = (tid & 15) << 2;

  const float* Aload = A + (long)(blockIdx.y * 64 + ar) * lda + ak4;
  const float* Bload = B + (long)br * ldb + blockIdx.x * 64 + bn4;

  for (int k0 = 0; k0 < K; k0 += 16) {
    const float4 av = *(const float4*)(Aload + k0);
    const float4 bv = *(const float4*)(Bload + (long)k0 * ldb);
    __syncthreads();
    As2[ak4 + 0][ar] = av.x;
    As2[ak4 + 1][ar] = av.y;
    As2[ak4 + 2][ar] = av.z;
    As2[ak4 + 3][ar] = av.w;
    *(float4*)&Bs2[br][bn4] = bv;
    __syncthreads();
#pragma unroll
    for (int kk = 0; kk < 16; ++kk) {
      const float4 a4 = *(const float4*)&As2[kk][ty << 2];
      const float4 b4 = *(const float4*)&Bs2[kk][tx << 2];
      const float am[4] = {a4.x, a4.y, a4.z, a4.w};
      const float bn[4] = {b4.x, b4.y, b4.z, b4.w};
#pragma unroll
      for (int i = 0; i < 4; ++i)
#pragma unroll
        for (int j = 0; j < 4; ++j) acc[i][j] = fmaf(am[i], bn[j], acc[i][j]);
    }
  }

  if (OMODE == 0) {
    const int row0 = blockIdx.y * 64 + (ty << 2);
    const int col0 = blockIdx.x * 64 + (tx << 2);
    float4 bb4 = make_float4(0.f, 0.f, 0.f, 0.f);
    if (BIAS) bb4 = *(const float4*)&bias[col0];
#pragma unroll
    for (int i = 0; i < 4; ++i) {
      float4 o;
      o.x = acc[i][0] + bb4.x;
      o.y = acc[i][1] + bb4.y;
      o.z = acc[i][2] + bb4.z;
      o.w = acc[i][3] + bb4.w;
      *(float4*)&C[(long)(row0 + i) * ldc + col0] = o;
    }
  } else {
#pragma unroll
    for (int i = 0; i < 4; ++i) {
      const int gr = blockIdx.y * 64 + (ty << 2) + i;
      const int b = gr >> 10;
      const int e = gr & 1023;
#pragma unroll
      for (int j = 0; j < 4; ++j) {
        const int col = blockIdx.x * 64 + (tx << 2) + j;
        C[(long)b * (ATTN_A * ENC_LEN) + (long)col * ENC_LEN + e] = acc[i][j];
      }
    }
  }
}

__global__ __launch_bounds__(256) void logits_fb(const float* __restrict__ peT,
                                                 const float* __restrict__ pd,
                                                 const float* __restrict__ v,
                                                 float* __restrict__ out) {
  const int tid = threadIdx.x;
  const int e = blockIdx.x * 256 + tid;
  const int d0 = blockIdx.y * 8;
  const int b = blockIdx.z;

  __shared__ float cpd[ATTN_A][8];
  __shared__ float vv[ATTN_A];

  {
    const int a = tid;
#pragma unroll
    for (int dd = 0; dd < 8; ++dd)
      cpd[a][dd] = C2F * pd[((b * DEC_LEN + d0 + dd) * ATTN_A) + a];
    vv[a] = -2.0f * v[a];
  }
  __syncthreads();

  float acc[8] = {0.f, 0.f, 0.f, 0.f, 0.f, 0.f, 0.f, 0.f};
  const float* pe = peT + (long)b * (ATTN_A * ENC_LEN) + e;

  for (int a = 0; a < ATTN_A; a += 4) {
    float pes[4];
#pragma unroll
    for (int u = 0; u < 4; ++u) pes[u] = pe[(long)(a + u) * ENC_LEN];
#pragma unroll
    for (int u = 0; u < 4; ++u) {
      const float cpe = C2F * pes[u];
      const float vu = vv[a + u];
      const float4 c0 = *(const float4*)&cpd[a + u][0];
      const float4 c1 = *(const float4*)&cpd[a + u][4];
      const float cd[8] = {c0.x, c0.y, c0.z, c0.w, c1.x, c1.y, c1.z, c1.w};
#pragma unroll
      for (int dd = 0; dd < 8; ++dd) {
        const float x = cd[dd] + cpe;
        const float ex = __builtin_amdgcn_exp2f(x);
        const float r = __builtin_amdgcn_rcpf(ex + 1.0f);
        acc[dd] = fmaf(vu, r, acc[dd]);
      }
    }
  }

  const long base = ((long)(b * DEC_LEN + d0) * ENC_LEN) + e;
#pragma unroll
  for (int dd = 0; dd < 8; ++dd) out[base + (long)dd * ENC_LEN] = acc[dd];
}

__global__ __launch_bounds__(256) void softmax_fb(float* __restrict__ attn,
                                                  const float* __restrict__ mask) {
  const int row = blockIdx.x;
  const int b = row >> 8;
  const int tid = threadIdx.x;
  float* rp = attn + (long)row * ENC_LEN;
  const float* mp = mask + b * ENC_LEN;

  float l[4], m[4];
#pragma unroll
  for (int j = 0; j < 4; ++j) {
    l[j] = rp[tid + 256 * j];
    m[j] = mp[tid + 256 * j];
  }

  __shared__ float redmax[4];
  __shared__ float redsum[4];
  const int lane = tid & 63;
  const int wid = tid >> 6;

  float tm = fmaxf(fmaxf(l[0], l[1]), fmaxf(l[2], l[3]));
#pragma unroll
  for (int off = 1; off < 64; off <<= 1) tm = fmaxf(tm, __shfl_xor(tm, off, 64));
  if (lane == 0) redmax[wid] = tm;
  __syncthreads();
  const float rmax = fmaxf(fmaxf(redmax[0], redmax[1]), fmaxf(redmax[2], redmax[3]));

  const float LOG2E = 1.4426950408889634f;
  float p[4];
  float ts = 0.f;
#pragma unroll
  for (int j = 0; j < 4; ++j) {
    p[j] = __builtin_amdgcn_exp2f((l[j] - rmax) * LOG2E) * m[j];
    ts += p[j];
  }
#pragma unroll
  for (int off = 1; off < 64; off <<= 1) ts += __shfl_xor(ts, off, 64);
  if (lane == 0) redsum[wid] = ts;
  __syncthreads();
  const float rsum = redsum[0] + redsum[1] + redsum[2] + redsum[3];

  const float inv = 1.0f / rsum;
#pragma unroll
  for (int j = 0; j < 4; ++j) rp[tid + 256 * j] = p[j] * inv;
}

// ---------------------------------------------------------------------------
extern "C" void kernel_launch(void* const* d_in, const int* in_sizes, int n_in,
                              void* d_out, int out_size, void* d_ws, size_t ws_size,
                              hipStream_t stream) {
  const float* enc = (const float*)d_in[0];
  const float* dec = (const float*)d_in[1];
  const float* mask = (const float*)d_in[2];
  const float* Wh = (const float*)d_in[3];
  const float* Ws = (const float*)d_in[4];
  const float* bs = (const float*)d_in[5];
  const float* v = (const float*)d_in[6];

  float* ctx = (float*)d_out;                      // [4,256,1024]
  float* attn = ctx + (long)BB * DEC_LEN * ENC_H;  // [4,256,1024]

  const size_t FAST_WS = (size_t)BB * ENC_H * ENC_LEN * 2;  // 8 MB

  if (ws_size >= FAST_WS) {
    // ws phase A: [pdE 1MB][peT 4MB]; WhT/WsT in ctx region (dead until end);
    // logits partials: p0 = attn, p1 = ctx (clobbers WhT/WsT after gemms);
    // ws phase B (after logits): encT 8MB overwrites pdE/peT.
    float* pdE = (float*)d_ws;
    float* peT = pdE + (long)BB * DEC_LEN * ATTN_A;
    unsigned short* encT = (unsigned short*)d_ws;
    unsigned short* WhT = (unsigned short*)ctx;
    unsigned short* WsT = WhT + (long)ATTN_A * ENC_H;

    // 1) both weight transposes
    transpose_w2<<<dim3(ATTN_A / 64, ENC_H / 64, 2), 256, 0, stream>>>(Wh, Ws, WhT,
                                                                       WsT);
    // 2) fused projections: pdE (exp2 form) + peT (C2-scaled)
    proj_gemm<<<dim3(ATTN_A / 64, 16 + (BB * ENC_LEN) / 64, 1), 256, 0, stream>>>(
        dec, enc, WsT, WhT, bs, pdE, peT);
    // 3) logits partials (a-split over 2 blocks)
    logits_k<<<dim3(ENC_LEN / 256, DEC_LEN / 8, BB * 2), 256, 0, stream>>>(
        peT, pdE, v, attn, ctx);
    // 4) masked softmax (p0+p1 -> attn)
    softmax2_k<<<dim3(BB * DEC_LEN, 1, 1), 256, 0, stream>>>(attn, ctx, mask);
    // 5) encT[b][h][e] (pdE/peT dead now)
    transpose_cvt<<<dim3(ENC_H / 64, ENC_LEN / 64, BB), 256, 0, stream>>>(
        enc, encT, ENC_LEN, ENC_H, (long)ENC_LEN * ENC_H, (long)ENC_H * ENC_LEN);
    // 6) ctx = attn @ enc
    ctx_gemm<<<dim3(ENC_H / 64, DEC_LEN / 64, BB), 256, 0, stream>>>(
        attn, encT, ctx, ENC_LEN, ENC_LEN, ENC_H, (long)DEC_LEN * ENC_LEN,
        (long)ENC_H * ENC_LEN, (long)DEC_LEN * ENC_H);
  } else {
    // fallback: proven fp32 path (5 MB ws)
    float* pd = (float*)d_ws;
    float* peT = pd + (long)BB * DEC_LEN * ATTN_A;

    gemm64<0, true><<<dim3(ATTN_A / 64, (BB * DEC_LEN) / 64, 1), 256, 0, stream>>>(
        dec, Ws, bs, pd, ENC_H, ENC_H, ATTN_A, ATTN_A, 0, 0, 0);
    gemm64<1, false><<<dim3(ATTN_A / 64, (BB * ENC_LEN) / 64, 1), 256, 0, stream>>>(
        enc, Wh, nullptr, peT, ENC_H, ENC_H, ATTN_A, 0, 0, 0, 0);
    logits_fb<<<dim3(ENC_LEN / 256, DEC_LEN / 8, BB), 256, 0, stream>>>(peT, pd, v,
                                                                        attn);
    softmax_fb<<<dim3(BB * DEC_LEN, 1, 1), 256, 0, stream>>>(attn, mask);
    gemm64<0, false><<<dim3(ENC_H / 64, DEC_LEN / 64, BB), 256, 0, stream>>>(
        attn, enc, nullptr, ctx, ENC_LEN, ENC_LEN, ENC_H, ENC_H,
        (long)DEC_LEN * ENC_LEN, (long)ENC_LEN * ENC_H, (long)DEC_LEN * ENC_H);
  }
}

// Round 6
// 150.820 us; speedup vs baseline: 2.0319x; 1.1229x over previous
//
#include <hip/hip_runtime.h>
#include <hip/hip_bf16.h>

// Problem dims (fixed by reference)
#define BB 4
#define ENC_LEN 1024
#define DEC_LEN 256
#define ENC_H 1024
#define ATTN_A 256

#define C2F 2.8853900817779268f  // 2*log2(e)

typedef short bf16x8 __attribute__((ext_vector_type(8)));
typedef float f32x4 __attribute__((ext_vector_type(4)));
typedef unsigned int u32x2 __attribute__((ext_vector_type(2)));

union F4U {
  float4 v;
  float f[4];
};
union Q2D {
  uint4 q;
  u32x2 d[2];
};
union BF8 {
  u32x2 d[2];
  bf16x8 v;
};

// fp32 -> bf16 round-to-nearest-even
static __device__ __forceinline__ unsigned short f2bf(float x) {
  union {
    float f;
    unsigned int u;
  } c;
  c.f = x;
  unsigned int r = c.u + 0x7FFFu + ((c.u >> 16) & 1u);
  return (unsigned short)(r >> 16);
}

// ---------------------------------------------------------------------------
// prep: ALL transposes in one dispatch (1152 blocks).
//  blocks [0,64):    Wh [1024h][256a] -> WhT [256a][1024h]
//  blocks [64,128):  Ws -> WsT
//  blocks [128,1152): enc[b][1024e][1024h] -> encT[b][1024h][1024e]
// ---------------------------------------------------------------------------
__global__ __launch_bounds__(256) void prep_k(const float* __restrict__ Wh,
                                              const float* __restrict__ Ws,
                                              const float* __restrict__ enc,
                                              unsigned short* __restrict__ WhT,
                                              unsigned short* __restrict__ WsT,
                                              unsigned short* __restrict__ encT) {
  __shared__ unsigned short T[64][68];
  const int wb = blockIdx.x;
  const float* in;
  unsigned short* out;
  int R, C, bx, by;
  if (wb < 128) {
    in = (wb < 64) ? Wh : Ws;
    out = (wb < 64) ? WhT : WsT;
    const int t = wb & 63;
    R = ENC_H;
    C = ATTN_A;
    bx = t & 3;
    by = t >> 2;
  } else {
    const int t = wb - 128;
    const int b = t >> 8;
    const int tt = t & 255;
    in = enc + (long)b * ENC_LEN * ENC_H;
    out = encT + (long)b * ENC_H * ENC_LEN;
    R = ENC_LEN;
    C = ENC_H;
    bx = tt & 15;
    by = tt >> 4;
  }
  const int r0 = by * 64;
  const int c0 = bx * 64;
  const int t = threadIdx.x;
  const int lr = t >> 4;
  const int lc4 = (t & 15) * 4;

#pragma unroll
  for (int p = 0; p < 4; ++p) {
    const int r = lr + p * 16;
    const float4 v = *(const float4*)&in[(long)(r0 + r) * C + c0 + lc4];
    ushort4 o;
    o.x = f2bf(v.x);
    o.y = f2bf(v.y);
    o.z = f2bf(v.z);
    o.w = f2bf(v.w);
    *(ushort4*)&T[r][lc4] = o;
  }
  __syncthreads();
#pragma unroll
  for (int p = 0; p < 4; ++p) {
    const int c = lr + p * 16;
    ushort4 o;
    o.x = T[lc4 + 0][c];
    o.y = T[lc4 + 1][c];
    o.z = T[lc4 + 2][c];
    o.w = T[lc4 + 3][c];
    *(ushort4*)&out[(long)(c0 + c) * R + r0 + lc4] = o;
  }
}

// ---------------------------------------------------------------------------
// K-split fused projection GEMM. grid (4, 80, 2); z = K-split half (K=512).
//  y <  16: pdP[s][m][a]  = C2*(dec-chunk · Ws-chunk)        (raw partial)
//  y >= 16: peP[s][b][a][e] = C2*(enc-chunk · Wh-chunk)      (LDS-transposed)
// Tile 64x64, BK=32, 4 waves of 2x2 mfma 16x16x32. Register prefetch: next
// iter's global loads issue before the MFMA section.
// ---------------------------------------------------------------------------
__global__ __launch_bounds__(256) void pgemm(const float* __restrict__ dec,
                                             const float* __restrict__ enc,
                                             const unsigned short* __restrict__ WsT,
                                             const unsigned short* __restrict__ WhT,
                                             float* __restrict__ pdP,
                                             float* __restrict__ peP) {
  __shared__ unsigned short As[64][36];
  __shared__ unsigned short Bs[64][36];
  __shared__ float Cs[64][68];

  const int s = blockIdx.z;
  const bool isPD = blockIdx.y < 16;
  const float* A = isPD ? dec : enc;
  const unsigned short* BT = isPD ? WsT : WhT;
  const int m0 = (isPD ? blockIdx.y : (blockIdx.y - 16)) * 64;
  const int n0 = blockIdx.x * 64;
  const int kb = s * 512;

  const int tid = threadIdx.x;
  const int lane = tid & 63;
  const int wave = tid >> 6;
  const int quad = lane >> 4;
  const int l16 = lane & 15;
  const int wm = (wave >> 1) * 32;
  const int wn = (wave & 1) * 32;
  const int sr = tid >> 2;
  const int sk = (tid & 3) * 8;

  f32x4 acc[2][2] = {{{0.f, 0.f, 0.f, 0.f}, {0.f, 0.f, 0.f, 0.f}},
                     {{0.f, 0.f, 0.f, 0.f}, {0.f, 0.f, 0.f, 0.f}}};

  const float* Ap = A + (long)(m0 + sr) * ENC_H + kb + sk;
  const unsigned short* Bp = BT + (long)(n0 + sr) * ENC_H + kb + sk;

  F4U a0, a1;
  Q2D bv;
  a0.v = *(const float4*)(Ap);
  a1.v = *(const float4*)(Ap + 4);
  bv.q = *(const uint4*)(Bp);

  for (int k0 = 0; k0 < 512; k0 += 32) {
    __syncthreads();
    Q2D av;
    av.q.x = (unsigned int)f2bf(a0.f[0]) | ((unsigned int)f2bf(a0.f[1]) << 16);
    av.q.y = (unsigned int)f2bf(a0.f[2]) | ((unsigned int)f2bf(a0.f[3]) << 16);
    av.q.z = (unsigned int)f2bf(a1.f[0]) | ((unsigned int)f2bf(a1.f[1]) << 16);
    av.q.w = (unsigned int)f2bf(a1.f[2]) | ((unsigned int)f2bf(a1.f[3]) << 16);
    *(u32x2*)&As[sr][sk] = av.d[0];
    *(u32x2*)&As[sr][sk + 4] = av.d[1];
    *(u32x2*)&Bs[sr][sk] = bv.d[0];
    *(u32x2*)&Bs[sr][sk + 4] = bv.d[1];
    // prefetch next iter (clamped: last iter redundantly reloads iter 0)
    const int kn = (k0 + 32 < 512) ? (k0 + 32) : 0;
    a0.v = *(const float4*)(Ap + kn);
    a1.v = *(const float4*)(Ap + kn + 4);
    bv.q = *(const uint4*)(Bp + kn);
    __syncthreads();

    bf16x8 af[2], bfr[2];
#pragma unroll
    for (int i = 0; i < 2; ++i) {
      BF8 t;
      t.d[0] = *(const u32x2*)&As[wm + i * 16 + l16][quad * 8];
      t.d[1] = *(const u32x2*)&As[wm + i * 16 + l16][quad * 8 + 4];
      af[i] = t.v;
    }
#pragma unroll
    for (int j = 0; j < 2; ++j) {
      BF8 t;
      t.d[0] = *(const u32x2*)&Bs[wn + j * 16 + l16][quad * 8];
      t.d[1] = *(const u32x2*)&Bs[wn + j * 16 + l16][quad * 8 + 4];
      bfr[j] = t.v;
    }
#pragma unroll
    for (int i = 0; i < 2; ++i)
#pragma unroll
      for (int j = 0; j < 2; ++j)
        acc[i][j] = __builtin_amdgcn_mfma_f32_16x16x32_bf16(af[i], bfr[j], acc[i][j],
                                                            0, 0, 0);
  }

  if (isPD) {
    float* out = pdP + (long)s * (1024 * ATTN_A);
#pragma unroll
    for (int j = 0; j < 2; ++j) {
      const int col = n0 + wn + j * 16 + l16;
#pragma unroll
      for (int i = 0; i < 2; ++i) {
        const int row = m0 + wm + i * 16 + quad * 4;
#pragma unroll
        for (int r = 0; r < 4; ++r)
          out[(long)(row + r) * ATTN_A + col] = C2F * acc[i][j][r];
      }
    }
  } else {
    __syncthreads();
#pragma unroll
    for (int i = 0; i < 2; ++i)
#pragma unroll
      for (int j = 0; j < 2; ++j)
#pragma unroll
        for (int r = 0; r < 4; ++r)
          Cs[wn + j * 16 + l16][wm + i * 16 + quad * 4 + r] = C2F * acc[i][j][r];
    __syncthreads();
    const int gb = m0 >> 10;
    const int e0 = m0 & 1023;
    float* out = peP + (long)s * (BB * ATTN_A * ENC_LEN);
#pragma unroll
    for (int p = 0; p < 4; ++p) {
      const int arow = (tid >> 4) + p * 16;
      const int e4 = (tid & 15) * 4;
      const float4 o = *(const float4*)&Cs[arow][e4];
      *(float4*)&out[(long)gb * (ATTN_A * ENC_LEN) + (long)(n0 + arow) * ENC_LEN +
                     e0 + e4] = o;
    }
  }
}

// ---------------------------------------------------------------------------
// Logits: Ed = exp2(pd0+pd1+C2*bs) (K-split partials summed here);
// Ee = exp2(pe0+pe1); part += (-2 v_a)*rcp(Ed*Ee+1).
// Grid (4, 32, 8): z = b*2 + ahalf. Partials to p0 (attn) / p1 (ws).
// ---------------------------------------------------------------------------
__global__ __launch_bounds__(256) void logits_k(const float* __restrict__ peP,
                                                const float* __restrict__ pdP,
                                                const float* __restrict__ v,
                                                const float* __restrict__ bs,
                                                float* __restrict__ p0,
                                                float* __restrict__ p1) {
  const int tid = threadIdx.x;
  const int e = blockIdx.x * 256 + tid;
  const int d0 = blockIdx.y * 8;
  const int b = blockIdx.z >> 1;
  const int a0 = (blockIdx.z & 1) * 128;

  __shared__ float Ed[128][8];
  __shared__ float vv[128];

  if (tid < 128) {
    const float cb = C2F * bs[a0 + tid];
#pragma unroll
    for (int dd = 0; dd < 8; ++dd) {
      const long idx = (long)(b * DEC_LEN + d0 + dd) * ATTN_A + a0 + tid;
      const float t = pdP[idx] + pdP[idx + 1024 * ATTN_A] + cb;
      Ed[tid][dd] = __builtin_amdgcn_exp2f(t);
    }
    vv[tid] = -2.0f * v[a0 + tid];
  }
  __syncthreads();

  float acc[8] = {0.f, 0.f, 0.f, 0.f, 0.f, 0.f, 0.f, 0.f};
  const float* pe0 = peP + (long)b * (ATTN_A * ENC_LEN) + (long)a0 * ENC_LEN + e;
  const float* pe1 = pe0 + (long)BB * ATTN_A * ENC_LEN;

  float pn0[4], pn1[4];
#pragma unroll
  for (int u = 0; u < 4; ++u) {
    pn0[u] = pe0[(long)u * ENC_LEN];
    pn1[u] = pe1[(long)u * ENC_LEN];
  }

  for (int a4 = 0; a4 < 128; a4 += 4) {
    float pes[4];
#pragma unroll
    for (int u = 0; u < 4; ++u) pes[u] = pn0[u] + pn1[u];
    const int an = (a4 + 4 < 128) ? (a4 + 4) : 0;
#pragma unroll
    for (int u = 0; u < 4; ++u) {
      pn0[u] = pe0[(long)(an + u) * ENC_LEN];
      pn1[u] = pe1[(long)(an + u) * ENC_LEN];
    }
#pragma unroll
    for (int u = 0; u < 4; ++u) {
      const float Ee = __builtin_amdgcn_exp2f(pes[u]);
      const float vu = vv[a4 + u];
      const float4 e0v = *(const float4*)&Ed[a4 + u][0];
      const float4 e1v = *(const float4*)&Ed[a4 + u][4];
      const float ed[8] = {e0v.x, e0v.y, e0v.z, e0v.w, e1v.x, e1v.y, e1v.z, e1v.w};
#pragma unroll
      for (int dd = 0; dd < 8; ++dd) {
        const float den = fmaf(ed[dd], Ee, 1.0f);
        const float r = __builtin_amdgcn_rcpf(den);
        acc[dd] = fmaf(vu, r, acc[dd]);
      }
    }
  }

  float* po = (blockIdx.z & 1) ? p1 : p0;
  const long base = ((long)(b * DEC_LEN + d0) * ENC_LEN) + e;
#pragma unroll
  for (int dd = 0; dd < 8; ++dd) po[base + (long)dd * ENC_LEN] = acc[dd];
}

// ---------------------------------------------------------------------------
// Masked softmax over e: logits = p0+p1; normalized result to p0 (attn).
// ---------------------------------------------------------------------------
__global__ __launch_bounds__(256) void softmax2_k(float* __restrict__ p0,
                                                  const float* __restrict__ p1,
                                                  const float* __restrict__ mask) {
  const int row = blockIdx.x;
  const int b = row >> 8;
  const int tid = threadIdx.x;
  float* rp = p0 + (long)row * ENC_LEN;
  const float* rq = p1 + (long)row * ENC_LEN;
  const float* mp = mask + b * ENC_LEN;

  float l[4], m[4];
#pragma unroll
  for (int j = 0; j < 4; ++j) {
    l[j] = rp[tid + 256 * j] + rq[tid + 256 * j];
    m[j] = mp[tid + 256 * j];
  }

  __shared__ float redmax[4];
  __shared__ float redsum[4];
  const int lane = tid & 63;
  const int wid = tid >> 6;

  float tm = fmaxf(fmaxf(l[0], l[1]), fmaxf(l[2], l[3]));
#pragma unroll
  for (int off = 1; off < 64; off <<= 1) tm = fmaxf(tm, __shfl_xor(tm, off, 64));
  if (lane == 0) redmax[wid] = tm;
  __syncthreads();
  const float rmax = fmaxf(fmaxf(redmax[0], redmax[1]), fmaxf(redmax[2], redmax[3]));

  const float LOG2E = 1.4426950408889634f;
  float p[4];
  float ts = 0.f;
#pragma unroll
  for (int j = 0; j < 4; ++j) {
    p[j] = __builtin_amdgcn_exp2f((l[j] - rmax) * LOG2E) * m[j];
    ts += p[j];
  }
#pragma unroll
  for (int off = 1; off < 64; off <<= 1) ts += __shfl_xor(ts, off, 64);
  if (lane == 0) redsum[wid] = ts;
  __syncthreads();
  const float rsum = redsum[0] + redsum[1] + redsum[2] + redsum[3];

  const float inv = 1.0f / rsum;
#pragma unroll
  for (int j = 0; j < 4; ++j) rp[tid + 256 * j] = p[j] * inv;
}

// ---------------------------------------------------------------------------
// K-split ctx GEMM: cP[s][b][d][h] = attn-chunk @ encT-chunk.
// grid (16, 4, 8): z = b*2 + s. Same tile/prefetch as pgemm.
// ---------------------------------------------------------------------------
__global__ __launch_bounds__(256) void cgemm(const float* __restrict__ attn,
                                             const unsigned short* __restrict__ encT,
                                             float* __restrict__ cP) {
  __shared__ unsigned short As[64][36];
  __shared__ unsigned short Bs[64][36];

  const int b = blockIdx.z >> 1;
  const int s = blockIdx.z & 1;
  const int kb = s * 512;
  const float* A = attn + (long)b * DEC_LEN * ENC_LEN;
  const unsigned short* BT = encT + (long)b * ENC_H * ENC_LEN;
  float* C = cP + (long)s * (BB * DEC_LEN * ENC_H) + (long)b * DEC_LEN * ENC_H;

  const int tid = threadIdx.x;
  const int lane = tid & 63;
  const int wave = tid >> 6;
  const int quad = lane >> 4;
  const int l16 = lane & 15;
  const int wm = (wave >> 1) * 32;
  const int wn = (wave & 1) * 32;
  const int m0 = blockIdx.y * 64;
  const int n0 = blockIdx.x * 64;
  const int sr = tid >> 2;
  const int sk = (tid & 3) * 8;

  f32x4 acc[2][2] = {{{0.f, 0.f, 0.f, 0.f}, {0.f, 0.f, 0.f, 0.f}},
                     {{0.f, 0.f, 0.f, 0.f}, {0.f, 0.f, 0.f, 0.f}}};

  const float* Ap = A + (long)(m0 + sr) * ENC_LEN + kb + sk;
  const unsigned short* Bp = BT + (long)(n0 + sr) * ENC_LEN + kb + sk;

  F4U a0, a1;
  Q2D bv;
  a0.v = *(const float4*)(Ap);
  a1.v = *(const float4*)(Ap + 4);
  bv.q = *(const uint4*)(Bp);

  for (int k0 = 0; k0 < 512; k0 += 32) {
    __syncthreads();
    Q2D av;
    av.q.x = (unsigned int)f2bf(a0.f[0]) | ((unsigned int)f2bf(a0.f[1]) << 16);
    av.q.y = (unsigned int)f2bf(a0.f[2]) | ((unsigned int)f2bf(a0.f[3]) << 16);
    av.q.z = (unsigned int)f2bf(a1.f[0]) | ((unsigned int)f2bf(a1.f[1]) << 16);
    av.q.w = (unsigned int)f2bf(a1.f[2]) | ((unsigned int)f2bf(a1.f[3]) << 16);
    *(u32x2*)&As[sr][sk] = av.d[0];
    *(u32x2*)&As[sr][sk + 4] = av.d[1];
    *(u32x2*)&Bs[sr][sk] = bv.d[0];
    *(u32x2*)&Bs[sr][sk + 4] = bv.d[1];
    const int kn = (k0 + 32 < 512) ? (k0 + 32) : 0;
    a0.v = *(const float4*)(Ap + kn);
    a1.v = *(const float4*)(Ap + kn + 4);
    bv.q = *(const uint4*)(Bp + kn);
    __syncthreads();

    bf16x8 af[2], bfr[2];
#pragma unroll
    for (int i = 0; i < 2; ++i) {
      BF8 t;
      t.d[0] = *(const u32x2*)&As[wm + i * 16 + l16][quad * 8];
      t.d[1] = *(const u32x2*)&As[wm + i * 16 + l16][quad * 8 + 4];
      af[i] = t.v;
    }
#pragma unroll
    for (int j = 0; j < 2; ++j) {
      BF8 t;
      t.d[0] = *(const u32x2*)&Bs[wn + j * 16 + l16][quad * 8];
      t.d[1] = *(const u32x2*)&Bs[wn + j * 16 + l16][quad * 8 + 4];
      bfr[j] = t.v;
    }
#pragma unroll
    for (int i = 0; i < 2; ++i)
#pragma unroll
      for (int j = 0; j < 2; ++j)
        acc[i][j] = __builtin_amdgcn_mfma_f32_16x16x32_bf16(af[i], bfr[j], acc[i][j],
                                                            0, 0, 0);
  }

#pragma unroll
  for (int j = 0; j < 2; ++j) {
    const int col = n0 + wn + j * 16 + l16;
#pragma unroll
    for (int i = 0; i < 2; ++i) {
      const int row = m0 + wm + i * 16 + quad * 4;
#pragma unroll
      for (int r = 0; r < 4; ++r) C[(long)(row + r) * ENC_H + col] = acc[i][j][r];
    }
  }
}

// ctx = cP0 + cP1. ctx has BB*DEC*ENC_H = 1,048,576 floats; 4 floats/thread
// -> grid 1024 blocks x 256 threads. (R5 bug: 4096 blocks overran d_out.)
__global__ __launch_bounds__(256) void creduce(const float* __restrict__ cP,
                                               float* __restrict__ ctx) {
  const long i = ((long)blockIdx.x * 256 + threadIdx.x) * 4;
  const float4 x = *(const float4*)&cP[i];
  const float4 y = *(const float4*)&cP[i + (long)BB * DEC_LEN * ENC_H];
  float4 o;
  o.x = x.x + y.x;
  o.y = x.y + y.y;
  o.z = x.z + y.z;
  o.w = x.w + y.w;
  *(float4*)&ctx[i] = o;
}

// ---------------------------------------------------------------------------
// Fallback fp32 path kernels (proven, used only if ws too small)
// ---------------------------------------------------------------------------
template <int OMODE, bool BIAS>
__global__ __launch_bounds__(256) void gemm64(const float* __restrict__ A,
                                              const float* __restrict__ B,
                                              const float* __restrict__ bias,
                                              float* __restrict__ C,
                                              int K, int lda, int ldb, int ldc,
                                              long sA, long sB, long sC) {
  const int bz = blockIdx.z;
  A += (long)bz * sA;
  B += (long)bz * sB;
  C += (long)bz * sC;

  const int tid = threadIdx.x;
  const int tx = tid & 15;
  const int ty = tid >> 4;

  __shared__ float As2[16][64];
  __shared__ float Bs2[16][64];

  float acc[4][4];
#pragma unroll
  for (int i = 0; i < 4; ++i)
#pragma unroll
    for (int j = 0; j < 4; ++j) acc[i][j] = 0.f;

  const int ar = tid >> 2;
  const int ak4 = (tid & 3) << 2;
  const int br = tid >> 4;
  const int bn4 = (tid & 15) << 2;

  const float* Aload = A + (long)(blockIdx.y * 64 + ar) * lda + ak4;
  const float* Bload = B + (long)br * ldb + blockIdx.x * 64 + bn4;

  for (int k0 = 0; k0 < K; k0 += 16) {
    const float4 av = *(const float4*)(Aload + k0);
    const float4 bv = *(const float4*)(Bload + (long)k0 * ldb);
    __syncthreads();
    As2[ak4 + 0][ar] = av.x;
    As2[ak4 + 1][ar] = av.y;
    As2[ak4 + 2][ar] = av.z;
    As2[ak4 + 3][ar] = av.w;
    *(float4*)&Bs2[br][bn4] = bv;
    __syncthreads();
#pragma unroll
    for (int kk = 0; kk < 16; ++kk) {
      const float4 a4 = *(const float4*)&As2[kk][ty << 2];
      const float4 b4 = *(const float4*)&Bs2[kk][tx << 2];
      const float am[4] = {a4.x, a4.y, a4.z, a4.w};
      const float bn[4] = {b4.x, b4.y, b4.z, b4.w};
#pragma unroll
      for (int i = 0; i < 4; ++i)
#pragma unroll
        for (int j = 0; j < 4; ++j) acc[i][j] = fmaf(am[i], bn[j], acc[i][j]);
    }
  }

  if (OMODE == 0) {
    const int row0 = blockIdx.y * 64 + (ty << 2);
    const int col0 = blockIdx.x * 64 + (tx << 2);
    float4 bb4 = make_float4(0.f, 0.f, 0.f, 0.f);
    if (BIAS) bb4 = *(const float4*)&bias[col0];
#pragma unroll
    for (int i = 0; i < 4; ++i) {
      float4 o;
      o.x = acc[i][0] + bb4.x;
      o.y = acc[i][1] + bb4.y;
      o.z = acc[i][2] + bb4.z;
      o.w = acc[i][3] + bb4.w;
      *(float4*)&C[(long)(row0 + i) * ldc + col0] = o;
    }
  } else {
#pragma unroll
    for (int i = 0; i < 4; ++i) {
      const int gr = blockIdx.y * 64 + (ty << 2) + i;
      const int b = gr >> 10;
      const int e = gr & 1023;
#pragma unroll
      for (int j = 0; j < 4; ++j) {
        const int col = blockIdx.x * 64 + (tx << 2) + j;
        C[(long)b * (ATTN_A * ENC_LEN) + (long)col * ENC_LEN + e] = acc[i][j];
      }
    }
  }
}

__global__ __launch_bounds__(256) void logits_fb(const float* __restrict__ peT,
                                                 const float* __restrict__ pd,
                                                 const float* __restrict__ v,
                                                 float* __restrict__ out) {
  const int tid = threadIdx.x;
  const int e = blockIdx.x * 256 + tid;
  const int d0 = blockIdx.y * 8;
  const int b = blockIdx.z;

  __shared__ float cpd[ATTN_A][8];
  __shared__ float vv[ATTN_A];

  {
    const int a = tid;
#pragma unroll
    for (int dd = 0; dd < 8; ++dd)
      cpd[a][dd] = C2F * pd[((b * DEC_LEN + d0 + dd) * ATTN_A) + a];
    vv[a] = -2.0f * v[a];
  }
  __syncthreads();

  float acc[8] = {0.f, 0.f, 0.f, 0.f, 0.f, 0.f, 0.f, 0.f};
  const float* pe = peT + (long)b * (ATTN_A * ENC_LEN) + e;

  for (int a = 0; a < ATTN_A; a += 4) {
    float pes[4];
#pragma unroll
    for (int u = 0; u < 4; ++u) pes[u] = pe[(long)(a + u) * ENC_LEN];
#pragma unroll
    for (int u = 0; u < 4; ++u) {
      const float cpe = C2F * pes[u];
      const float vu = vv[a + u];
      const float4 c0 = *(const float4*)&cpd[a + u][0];
      const float4 c1 = *(const float4*)&cpd[a + u][4];
      const float cd[8] = {c0.x, c0.y, c0.z, c0.w, c1.x, c1.y, c1.z, c1.w};
#pragma unroll
      for (int dd = 0; dd < 8; ++dd) {
        const float x = cd[dd] + cpe;
        const float ex = __builtin_amdgcn_exp2f(x);
        const float r = __builtin_amdgcn_rcpf(ex + 1.0f);
        acc[dd] = fmaf(vu, r, acc[dd]);
      }
    }
  }

  const long base = ((long)(b * DEC_LEN + d0) * ENC_LEN) + e;
#pragma unroll
  for (int dd = 0; dd < 8; ++dd) out[base + (long)dd * ENC_LEN] = acc[dd];
}

__global__ __launch_bounds__(256) void softmax_fb(float* __restrict__ attn,
                                                  const float* __restrict__ mask) {
  const int row = blockIdx.x;
  const int b = row >> 8;
  const int tid = threadIdx.x;
  float* rp = attn + (long)row * ENC_LEN;
  const float* mp = mask + b * ENC_LEN;

  float l[4], m[4];
#pragma unroll
  for (int j = 0; j < 4; ++j) {
    l[j] = rp[tid + 256 * j];
    m[j] = mp[tid + 256 * j];
  }

  __shared__ float redmax[4];
  __shared__ float redsum[4];
  const int lane = tid & 63;
  const int wid = tid >> 6;

  float tm = fmaxf(fmaxf(l[0], l[1]), fmaxf(l[2], l[3]));
#pragma unroll
  for (int off = 1; off < 64; off <<= 1) tm = fmaxf(tm, __shfl_xor(tm, off, 64));
  if (lane == 0) redmax[wid] = tm;
  __syncthreads();
  const float rmax = fmaxf(fmaxf(redmax[0], redmax[1]), fmaxf(redmax[2], redmax[3]));

  const float LOG2E = 1.4426950408889634f;
  float p[4];
  float ts = 0.f;
#pragma unroll
  for (int j = 0; j < 4; ++j) {
    p[j] = __builtin_amdgcn_exp2f((l[j] - rmax) * LOG2E) * m[j];
    ts += p[j];
  }
#pragma unroll
  for (int off = 1; off < 64; off <<= 1) ts += __shfl_xor(ts, off, 64);
  if (lane == 0) redsum[wid] = ts;
  __syncthreads();
  const float rsum = redsum[0] + redsum[1] + redsum[2] + redsum[3];

  const float inv = 1.0f / rsum;
#pragma unroll
  for (int j = 0; j < 4; ++j) rp[tid + 256 * j] = p[j] * inv;
}

// ---------------------------------------------------------------------------
extern "C" void kernel_launch(void* const* d_in, const int* in_sizes, int n_in,
                              void* d_out, int out_size, void* d_ws, size_t ws_size,
                              hipStream_t stream) {
  const float* enc = (const float*)d_in[0];
  const float* dec = (const float*)d_in[1];
  const float* mask = (const float*)d_in[2];
  const float* Wh = (const float*)d_in[3];
  const float* Ws = (const float*)d_in[4];
  const float* bs = (const float*)d_in[5];
  const float* v = (const float*)d_in[6];

  float* ctx = (float*)d_out;                      // [4,256,1024]
  float* attn = ctx + (long)BB * DEC_LEN * ENC_H;  // [4,256,1024]

  // ws layout (fast path), floats unless noted:
  //  pdP  [2][1024][256]            2 MB
  //  peP  [2][4][256][1024]         8 MB
  //  p1   [4][256][1024]            4 MB (logits partial, ahalf=1)
  //  cP   [2][4][256][1024]         8 MB
  //  encT bf16 [4][1024][1024]      8 MB
  //  WhT/WsT bf16 [256][1024]       1 MB
  const long N_PD = 2L * 1024 * ATTN_A;
  const long N_PE = 2L * BB * ATTN_A * ENC_LEN;
  const long N_P1 = (long)BB * DEC_LEN * ENC_LEN;
  const long N_CP = 2L * BB * DEC_LEN * ENC_H;
  const size_t FAST_WS = (N_PD + N_PE + N_P1 + N_CP) * 4 +
                         ((long)BB * ENC_H * ENC_LEN + 2L * ATTN_A * ENC_H) * 2;

  if (ws_size >= FAST_WS) {
    float* pdP = (float*)d_ws;
    float* peP = pdP + N_PD;
    float* p1 = peP + N_PE;
    float* cP = p1 + N_P1;
    unsigned short* encT = (unsigned short*)(cP + N_CP);
    unsigned short* WhT = encT + (long)BB * ENC_H * ENC_LEN;
    unsigned short* WsT = WhT + (long)ATTN_A * ENC_H;

    // 1) all transposes (WhT, WsT, encT)
    prep_k<<<dim3(1152, 1, 1), 256, 0, stream>>>(Wh, Ws, enc, WhT, WsT, encT);
    // 2) K-split fused projections
    pgemm<<<dim3(4, 80, 2), 256, 0, stream>>>(dec, enc, WsT, WhT, pdP, peP);
    // 3) logits partials (a-split x2), partial-sum + bias + exp fused
    logits_k<<<dim3(4, 32, BB * 2), 256, 0, stream>>>(peP, pdP, v, bs, attn, p1);
    // 4) masked softmax (p0+p1 -> attn)
    softmax2_k<<<dim3(BB * DEC_LEN, 1, 1), 256, 0, stream>>>(attn, p1, mask);
    // 5) K-split ctx GEMM
    cgemm<<<dim3(16, 4, BB * 2), 256, 0, stream>>>(attn, encT, cP);
    // 6) ctx = cP0 + cP1 (1024 blocks — exactly 1,048,576 floats)
    creduce<<<dim3(1024, 1, 1), 256, 0, stream>>>(cP, ctx);
  } else {
    // fallback: proven fp32 path (5 MB ws)
    float* pd = (float*)d_ws;
    float* peT = pd + (long)BB * DEC_LEN * ATTN_A;

    gemm64<0, true><<<dim3(ATTN_A / 64, (BB * DEC_LEN) / 64, 1), 256, 0, stream>>>(
        dec, Ws, bs, pd, ENC_H, ENC_H, ATTN_A, ATTN_A, 0, 0, 0);
    gemm64<1, false><<<dim3(ATTN_A / 64, (BB * ENC_LEN) / 64, 1), 256, 0, stream>>>(
        enc, Wh, nullptr, peT, ENC_H, ENC_H, ATTN_A, 0, 0, 0, 0);
    logits_fb<<<dim3(ENC_LEN / 256, DEC_LEN / 8, BB), 256, 0, stream>>>(peT, pd, v,
                                                                        attn);
    softmax_fb<<<dim3(BB * DEC_LEN, 1, 1), 256, 0, stream>>>(attn, mask);
    gemm64<0, false><<<dim3(ENC_H / 64, DEC_LEN / 64, BB), 256, 0, stream>>>(
        attn, enc, nullptr, ctx, ENC_LEN, ENC_LEN, ENC_H, ENC_H,
        (long)DEC_LEN * ENC_LEN, (long)ENC_LEN * ENC_H, (long)DEC_LEN * ENC_H);
  }
}

// Round 7
// 143.269 us; speedup vs baseline: 2.1390x; 1.0527x over previous
//
#include <hip/hip_runtime.h>
#include <hip/hip_bf16.h>

// Problem dims (fixed by reference)
#define BB 4
#define ENC_LEN 1024
#define DEC_LEN 256
#define ENC_H 1024
#define ATTN_A 256

#define C2F 2.8853900817779268f  // 2*log2(e)

typedef short bf16x8 __attribute__((ext_vector_type(8)));
typedef float f32x4 __attribute__((ext_vector_type(4)));
typedef unsigned int u32x2 __attribute__((ext_vector_type(2)));

union Q2D {
  uint4 q;
  u32x2 d[2];
};
union BF8 {
  u32x2 d[2];
  bf16x8 v;
};

// fp32 -> bf16 round-to-nearest-even
static __device__ __forceinline__ unsigned short f2bf(float x) {
  union {
    float f;
    unsigned int u;
  } c;
  c.f = x;
  unsigned int r = c.u + 0x7FFFu + ((c.u >> 16) & 1u);
  return (unsigned short)(r >> 16);
}

// ---------------------------------------------------------------------------
// prep: all conversions/transposes in one dispatch (1408 blocks).
//  [0,64):      Wh [1024h][256a] -> WhT bf16 [256a][1024h]
//  [64,128):    Ws -> WsT
//  [128,1152):  enc[b][e][h] -> encT bf16 [b][h][e]  AND  encB bf16 [b][e][h]
//  [1152,1408): dec -> decB bf16 (row-major convert only)
// ---------------------------------------------------------------------------
__global__ __launch_bounds__(256) void prep_k(
    const float* __restrict__ Wh, const float* __restrict__ Ws,
    const float* __restrict__ enc, const float* __restrict__ dec,
    unsigned short* __restrict__ WhT, unsigned short* __restrict__ WsT,
    unsigned short* __restrict__ encT, unsigned short* __restrict__ encB,
    unsigned short* __restrict__ decB) {
  __shared__ unsigned short T[64][68];
  const int wb = blockIdx.x;
  const int t = threadIdx.x;
  const int lr = t >> 4;
  const int lc4 = (t & 15) * 4;

  if (wb >= 1152) {
    // dec row-major bf16 convert: collapsed [1024][1024]
    const int q = wb - 1152;
    const int r0 = (q >> 4) * 64;
    const int c0 = (q & 15) * 64;
#pragma unroll
    for (int p = 0; p < 4; ++p) {
      const int r = lr + p * 16;
      const float4 v = *(const float4*)&dec[(long)(r0 + r) * ENC_H + c0 + lc4];
      ushort4 o;
      o.x = f2bf(v.x);
      o.y = f2bf(v.y);
      o.z = f2bf(v.z);
      o.w = f2bf(v.w);
      *(ushort4*)&decB[(long)(r0 + r) * ENC_H + c0 + lc4] = o;
    }
    return;
  }

  const float* in;
  unsigned short* out;
  unsigned short* out2 = nullptr;  // row-major bf16 copy (enc only)
  int R, C, bx, by;
  if (wb < 128) {
    in = (wb < 64) ? Wh : Ws;
    out = (wb < 64) ? WhT : WsT;
    const int tt = wb & 63;
    R = ENC_H;
    C = ATTN_A;
    bx = tt & 3;
    by = tt >> 2;
  } else {
    const int tt0 = wb - 128;
    const int b = tt0 >> 8;
    const int tt = tt0 & 255;
    in = enc + (long)b * ENC_LEN * ENC_H;
    out = encT + (long)b * ENC_H * ENC_LEN;
    out2 = encB + (long)b * ENC_LEN * ENC_H;
    R = ENC_LEN;
    C = ENC_H;
    bx = tt & 15;
    by = tt >> 4;
  }
  const int r0 = by * 64;
  const int c0 = bx * 64;

#pragma unroll
  for (int p = 0; p < 4; ++p) {
    const int r = lr + p * 16;
    const float4 v = *(const float4*)&in[(long)(r0 + r) * C + c0 + lc4];
    ushort4 o;
    o.x = f2bf(v.x);
    o.y = f2bf(v.y);
    o.z = f2bf(v.z);
    o.w = f2bf(v.w);
    *(ushort4*)&T[r][lc4] = o;
    if (out2) *(ushort4*)&out2[(long)(r0 + r) * C + c0 + lc4] = o;
  }
  __syncthreads();
#pragma unroll
  for (int p = 0; p < 4; ++p) {
    const int c = lr + p * 16;
    ushort4 o;
    o.x = T[lc4 + 0][c];
    o.y = T[lc4 + 1][c];
    o.z = T[lc4 + 2][c];
    o.w = T[lc4 + 3][c];
    *(ushort4*)&out[(long)(c0 + c) * R + r0 + lc4] = o;
  }
}

// ---------------------------------------------------------------------------
// K-split fused projection GEMM, all-bf16 operands. grid (4, 80, 2).
//  y <  16: pdP[s][m][a]   = C2*(decB-chunk · WsT-chunk)     (raw partial)
//  y >= 16: peP[s][b][a][e] = C2*(encB-chunk · WhT-chunk)    (LDS-transposed)
// Tile 64x64, BK=32, 4 waves of 2x2 mfma 16x16x32, register prefetch.
// ---------------------------------------------------------------------------
__global__ __launch_bounds__(256) void pgemm(const unsigned short* __restrict__ decB,
                                             const unsigned short* __restrict__ encB,
                                             const unsigned short* __restrict__ WsT,
                                             const unsigned short* __restrict__ WhT,
                                             float* __restrict__ pdP,
                                             float* __restrict__ peP) {
  __shared__ unsigned short As[64][36];
  __shared__ unsigned short Bs[64][36];
  __shared__ float Cs[64][68];

  const int s = blockIdx.z;
  const bool isPD = blockIdx.y < 16;
  const unsigned short* A = isPD ? decB : encB;
  const unsigned short* BT = isPD ? WsT : WhT;
  const int m0 = (isPD ? blockIdx.y : (blockIdx.y - 16)) * 64;
  const int n0 = blockIdx.x * 64;
  const int kb = s * 512;

  const int tid = threadIdx.x;
  const int lane = tid & 63;
  const int wave = tid >> 6;
  const int quad = lane >> 4;
  const int l16 = lane & 15;
  const int wm = (wave >> 1) * 32;
  const int wn = (wave & 1) * 32;
  const int sr = tid >> 2;
  const int sk = (tid & 3) * 8;

  f32x4 acc[2][2] = {{{0.f, 0.f, 0.f, 0.f}, {0.f, 0.f, 0.f, 0.f}},
                     {{0.f, 0.f, 0.f, 0.f}, {0.f, 0.f, 0.f, 0.f}}};

  const unsigned short* Ap = A + (long)(m0 + sr) * ENC_H + kb + sk;
  const unsigned short* Bp = BT + (long)(n0 + sr) * ENC_H + kb + sk;

  Q2D av, bv;
  av.q = *(const uint4*)(Ap);
  bv.q = *(const uint4*)(Bp);

  for (int k0 = 0; k0 < 512; k0 += 32) {
    __syncthreads();
    *(u32x2*)&As[sr][sk] = av.d[0];
    *(u32x2*)&As[sr][sk + 4] = av.d[1];
    *(u32x2*)&Bs[sr][sk] = bv.d[0];
    *(u32x2*)&Bs[sr][sk + 4] = bv.d[1];
    const int kn = (k0 + 32 < 512) ? (k0 + 32) : 0;
    av.q = *(const uint4*)(Ap + kn);
    bv.q = *(const uint4*)(Bp + kn);
    __syncthreads();

    bf16x8 af[2], bfr[2];
#pragma unroll
    for (int i = 0; i < 2; ++i) {
      BF8 t;
      t.d[0] = *(const u32x2*)&As[wm + i * 16 + l16][quad * 8];
      t.d[1] = *(const u32x2*)&As[wm + i * 16 + l16][quad * 8 + 4];
      af[i] = t.v;
    }
#pragma unroll
    for (int j = 0; j < 2; ++j) {
      BF8 t;
      t.d[0] = *(const u32x2*)&Bs[wn + j * 16 + l16][quad * 8];
      t.d[1] = *(const u32x2*)&Bs[wn + j * 16 + l16][quad * 8 + 4];
      bfr[j] = t.v;
    }
#pragma unroll
    for (int i = 0; i < 2; ++i)
#pragma unroll
      for (int j = 0; j < 2; ++j)
        acc[i][j] = __builtin_amdgcn_mfma_f32_16x16x32_bf16(af[i], bfr[j], acc[i][j],
                                                            0, 0, 0);
  }

  if (isPD) {
    float* out = pdP + (long)s * (1024 * ATTN_A);
#pragma unroll
    for (int j = 0; j < 2; ++j) {
      const int col = n0 + wn + j * 16 + l16;
#pragma unroll
      for (int i = 0; i < 2; ++i) {
        const int row = m0 + wm + i * 16 + quad * 4;
#pragma unroll
        for (int r = 0; r < 4; ++r)
          out[(long)(row + r) * ATTN_A + col] = C2F * acc[i][j][r];
      }
    }
  } else {
    __syncthreads();
#pragma unroll
    for (int i = 0; i < 2; ++i)
#pragma unroll
      for (int j = 0; j < 2; ++j)
#pragma unroll
        for (int r = 0; r < 4; ++r)
          Cs[wn + j * 16 + l16][wm + i * 16 + quad * 4 + r] = C2F * acc[i][j][r];
    __syncthreads();
    const int gb = m0 >> 10;
    const int e0 = m0 & 1023;
    float* out = peP + (long)s * (BB * ATTN_A * ENC_LEN);
#pragma unroll
    for (int p = 0; p < 4; ++p) {
      const int arow = (tid >> 4) + p * 16;
      const int e4 = (tid & 15) * 4;
      const float4 o = *(const float4*)&Cs[arow][e4];
      *(float4*)&out[(long)gb * (ATTN_A * ENC_LEN) + (long)(n0 + arow) * ENC_LEN +
                     e0 + e4] = o;
    }
  }
}

// ---------------------------------------------------------------------------
// Logits, batched-rcp: Ed = exp2(pd0+pd1+C2*bs); Ee = exp2(pe0+pe1);
// den_u = Ed_u*Ee_u + 1. Four terms share ONE rcp:
//   sum_u v_u/den_u = (t1*x34 + t2*x12) / (x12*x34),
//   x12=d0*d1, x34=d2*d3, t1=v0*d1+v1*d0, t2=v2*d3+v3*d2.
// Grid (4, 32, 8): z = b*2 + ahalf. Partials to p0 (attn) / p1 (ws).
// ---------------------------------------------------------------------------
__global__ __launch_bounds__(256) void logits_k(const float* __restrict__ peP,
                                                const float* __restrict__ pdP,
                                                const float* __restrict__ v,
                                                const float* __restrict__ bs,
                                                float* __restrict__ p0,
                                                float* __restrict__ p1) {
  const int tid = threadIdx.x;
  const int e = blockIdx.x * 256 + tid;
  const int d0 = blockIdx.y * 8;
  const int b = blockIdx.z >> 1;
  const int a0 = (blockIdx.z & 1) * 128;

  __shared__ float Ed[128][8];
  __shared__ float vv[128];

  if (tid < 128) {
    const float cb = C2F * bs[a0 + tid];
#pragma unroll
    for (int dd = 0; dd < 8; ++dd) {
      const long idx = (long)(b * DEC_LEN + d0 + dd) * ATTN_A + a0 + tid;
      const float t = pdP[idx] + pdP[idx + 1024 * ATTN_A] + cb;
      Ed[tid][dd] = __builtin_amdgcn_exp2f(t);
    }
    vv[tid] = -2.0f * v[a0 + tid];
  }
  __syncthreads();

  float acc[8] = {0.f, 0.f, 0.f, 0.f, 0.f, 0.f, 0.f, 0.f};
  const float* pe0 = peP + (long)b * (ATTN_A * ENC_LEN) + (long)a0 * ENC_LEN + e;
  const float* pe1 = pe0 + (long)BB * ATTN_A * ENC_LEN;

  float pn0[4], pn1[4];
#pragma unroll
  for (int u = 0; u < 4; ++u) {
    pn0[u] = pe0[(long)u * ENC_LEN];
    pn1[u] = pe1[(long)u * ENC_LEN];
  }

  for (int a4 = 0; a4 < 128; a4 += 4) {
    float Ee[4];
#pragma unroll
    for (int u = 0; u < 4; ++u) Ee[u] = __builtin_amdgcn_exp2f(pn0[u] + pn1[u]);
    const int an = (a4 + 4 < 128) ? (a4 + 4) : 0;
#pragma unroll
    for (int u = 0; u < 4; ++u) {
      pn0[u] = pe0[(long)(an + u) * ENC_LEN];
      pn1[u] = pe1[(long)(an + u) * ENC_LEN];
    }
    const float4 v4 = *(const float4*)&vv[a4];

    float ed[4][8];
#pragma unroll
    for (int u = 0; u < 4; ++u) {
      const float4 e0v = *(const float4*)&Ed[a4 + u][0];
      const float4 e1v = *(const float4*)&Ed[a4 + u][4];
      ed[u][0] = e0v.x;
      ed[u][1] = e0v.y;
      ed[u][2] = e0v.z;
      ed[u][3] = e0v.w;
      ed[u][4] = e1v.x;
      ed[u][5] = e1v.y;
      ed[u][6] = e1v.z;
      ed[u][7] = e1v.w;
    }

#pragma unroll
    for (int dd = 0; dd < 8; ++dd) {
      const float dn0 = fmaf(ed[0][dd], Ee[0], 1.0f);
      const float dn1 = fmaf(ed[1][dd], Ee[1], 1.0f);
      const float dn2 = fmaf(ed[2][dd], Ee[2], 1.0f);
      const float dn3 = fmaf(ed[3][dd], Ee[3], 1.0f);
      const float x12 = dn0 * dn1;
      const float x34 = dn2 * dn3;
      float t1 = v4.x * dn1;
      t1 = fmaf(v4.y, dn0, t1);
      float t2 = v4.z * dn3;
      t2 = fmaf(v4.w, dn2, t2);
      float num = t1 * x34;
      num = fmaf(t2, x12, num);
      const float D = x12 * x34;
      const float r = __builtin_amdgcn_rcpf(D);
      acc[dd] = fmaf(num, r, acc[dd]);
    }
  }

  float* po = (blockIdx.z & 1) ? p1 : p0;
  const long base = ((long)(b * DEC_LEN + d0) * ENC_LEN) + e;
#pragma unroll
  for (int dd = 0; dd < 8; ++dd) po[base + (long)dd * ENC_LEN] = acc[dd];
}

// ---------------------------------------------------------------------------
// Masked softmax over e: logits = p0+p1; fp32 result to p0 (attn, output) and
// bf16 copy to attnB (for cgemm).
// ---------------------------------------------------------------------------
__global__ __launch_bounds__(256) void softmax2_k(float* __restrict__ p0,
                                                  const float* __restrict__ p1,
                                                  const float* __restrict__ mask,
                                                  unsigned short* __restrict__ attnB) {
  const int row = blockIdx.x;
  const int b = row >> 8;
  const int tid = threadIdx.x;
  float* rp = p0 + (long)row * ENC_LEN;
  const float* rq = p1 + (long)row * ENC_LEN;
  const float* mp = mask + b * ENC_LEN;
  unsigned short* rb = attnB + (long)row * ENC_LEN;

  float l[4], m[4];
#pragma unroll
  for (int j = 0; j < 4; ++j) {
    l[j] = rp[tid + 256 * j] + rq[tid + 256 * j];
    m[j] = mp[tid + 256 * j];
  }

  __shared__ float redmax[4];
  __shared__ float redsum[4];
  const int lane = tid & 63;
  const int wid = tid >> 6;

  float tm = fmaxf(fmaxf(l[0], l[1]), fmaxf(l[2], l[3]));
#pragma unroll
  for (int off = 1; off < 64; off <<= 1) tm = fmaxf(tm, __shfl_xor(tm, off, 64));
  if (lane == 0) redmax[wid] = tm;
  __syncthreads();
  const float rmax = fmaxf(fmaxf(redmax[0], redmax[1]), fmaxf(redmax[2], redmax[3]));

  const float LOG2E = 1.4426950408889634f;
  float p[4];
  float ts = 0.f;
#pragma unroll
  for (int j = 0; j < 4; ++j) {
    p[j] = __builtin_amdgcn_exp2f((l[j] - rmax) * LOG2E) * m[j];
    ts += p[j];
  }
#pragma unroll
  for (int off = 1; off < 64; off <<= 1) ts += __shfl_xor(ts, off, 64);
  if (lane == 0) redsum[wid] = ts;
  __syncthreads();
  const float rsum = redsum[0] + redsum[1] + redsum[2] + redsum[3];

  const float inv = 1.0f / rsum;
#pragma unroll
  for (int j = 0; j < 4; ++j) {
    const float w = p[j] * inv;
    rp[tid + 256 * j] = w;
    rb[tid + 256 * j] = f2bf(w);
  }
}

// ---------------------------------------------------------------------------
// K-split ctx GEMM (bf16 A): cP[s][b][d][h] = attnB-chunk @ encT-chunk.
// grid (16, 4, 8): z = b*2 + s.
// ---------------------------------------------------------------------------
__global__ __launch_bounds__(256) void cgemm(const unsigned short* __restrict__ attnB,
                                             const unsigned short* __restrict__ encT,
                                             float* __restrict__ cP) {
  __shared__ unsigned short As[64][36];
  __shared__ unsigned short Bs[64][36];

  const int b = blockIdx.z >> 1;
  const int s = blockIdx.z & 1;
  const int kb = s * 512;
  const unsigned short* A = attnB + (long)b * DEC_LEN * ENC_LEN;
  const unsigned short* BT = encT + (long)b * ENC_H * ENC_LEN;
  float* C = cP + (long)s * (BB * DEC_LEN * ENC_H) + (long)b * DEC_LEN * ENC_H;

  const int tid = threadIdx.x;
  const int lane = tid & 63;
  const int wave = tid >> 6;
  const int quad = lane >> 4;
  const int l16 = lane & 15;
  const int wm = (wave >> 1) * 32;
  const int wn = (wave & 1) * 32;
  const int m0 = blockIdx.y * 64;
  const int n0 = blockIdx.x * 64;
  const int sr = tid >> 2;
  const int sk = (tid & 3) * 8;

  f32x4 acc[2][2] = {{{0.f, 0.f, 0.f, 0.f}, {0.f, 0.f, 0.f, 0.f}},
                     {{0.f, 0.f, 0.f, 0.f}, {0.f, 0.f, 0.f, 0.f}}};

  const unsigned short* Ap = A + (long)(m0 + sr) * ENC_LEN + kb + sk;
  const unsigned short* Bp = BT + (long)(n0 + sr) * ENC_LEN + kb + sk;

  Q2D av, bv;
  av.q = *(const uint4*)(Ap);
  bv.q = *(const uint4*)(Bp);

  for (int k0 = 0; k0 < 512; k0 += 32) {
    __syncthreads();
    *(u32x2*)&As[sr][sk] = av.d[0];
    *(u32x2*)&As[sr][sk + 4] = av.d[1];
    *(u32x2*)&Bs[sr][sk] = bv.d[0];
    *(u32x2*)&Bs[sr][sk + 4] = bv.d[1];
    const int kn = (k0 + 32 < 512) ? (k0 + 32) : 0;
    av.q = *(const uint4*)(Ap + kn);
    bv.q = *(const uint4*)(Bp + kn);
    __syncthreads();

    bf16x8 af[2], bfr[2];
#pragma unroll
    for (int i = 0; i < 2; ++i) {
      BF8 t;
      t.d[0] = *(const u32x2*)&As[wm + i * 16 + l16][quad * 8];
      t.d[1] = *(const u32x2*)&As[wm + i * 16 + l16][quad * 8 + 4];
      af[i] = t.v;
    }
#pragma unroll
    for (int j = 0; j < 2; ++j) {
      BF8 t;
      t.d[0] = *(const u32x2*)&Bs[wn + j * 16 + l16][quad * 8];
      t.d[1] = *(const u32x2*)&Bs[wn + j * 16 + l16][quad * 8 + 4];
      bfr[j] = t.v;
    }
#pragma unroll
    for (int i = 0; i < 2; ++i)
#pragma unroll
      for (int j = 0; j < 2; ++j)
        acc[i][j] = __builtin_amdgcn_mfma_f32_16x16x32_bf16(af[i], bfr[j], acc[i][j],
                                                            0, 0, 0);
  }

#pragma unroll
  for (int j = 0; j < 2; ++j) {
    const int col = n0 + wn + j * 16 + l16;
#pragma unroll
    for (int i = 0; i < 2; ++i) {
      const int row = m0 + wm + i * 16 + quad * 4;
#pragma unroll
      for (int r = 0; r < 4; ++r) C[(long)(row + r) * ENC_H + col] = acc[i][j][r];
    }
  }
}

// ctx = cP0 + cP1: exactly BB*DEC*ENC_H = 1,048,576 floats -> 1024 blocks.
__global__ __launch_bounds__(256) void creduce(const float* __restrict__ cP,
                                               float* __restrict__ ctx) {
  const long i = ((long)blockIdx.x * 256 + threadIdx.x) * 4;
  const float4 x = *(const float4*)&cP[i];
  const float4 y = *(const float4*)&cP[i + (long)BB * DEC_LEN * ENC_H];
  float4 o;
  o.x = x.x + y.x;
  o.y = x.y + y.y;
  o.z = x.z + y.z;
  o.w = x.w + y.w;
  *(float4*)&ctx[i] = o;
}

// ---------------------------------------------------------------------------
// Fallback fp32 path kernels (proven, used only if ws too small)
// ---------------------------------------------------------------------------
template <int OMODE, bool BIAS>
__global__ __launch_bounds__(256) void gemm64(const float* __restrict__ A,
                                              const float* __restrict__ B,
                                              const float* __restrict__ bias,
                                              float* __restrict__ C,
                                              int K, int lda, int ldb, int ldc,
                                              long sA, long sB, long sC) {
  const int bz = blockIdx.z;
  A += (long)bz * sA;
  B += (long)bz * sB;
  C += (long)bz * sC;

  const int tid = threadIdx.x;
  const int tx = tid & 15;
  const int ty = tid >> 4;

  __shared__ float As2[16][64];
  __shared__ float Bs2[16][64];

  float acc[4][4];
#pragma unroll
  for (int i = 0; i < 4; ++i)
#pragma unroll
    for (int j = 0; j < 4; ++j) acc[i][j] = 0.f;

  const int ar = tid >> 2;
  const int ak4 = (tid & 3) << 2;
  const int br = tid >> 4;
  const int bn4 = (tid & 15) << 2;

  const float* Aload = A + (long)(blockIdx.y * 64 + ar) * lda + ak4;
  const float* Bload = B + (long)br * ldb + blockIdx.x * 64 + bn4;

  for (int k0 = 0; k0 < K; k0 += 16) {
    const float4 av = *(const float4*)(Aload + k0);
    const float4 bv = *(const float4*)(Bload + (long)k0 * ldb);
    __syncthreads();
    As2[ak4 + 0][ar] = av.x;
    As2[ak4 + 1][ar] = av.y;
    As2[ak4 + 2][ar] = av.z;
    As2[ak4 + 3][ar] = av.w;
    *(float4*)&Bs2[br][bn4] = bv;
    __syncthreads();
#pragma unroll
    for (int kk = 0; kk < 16; ++kk) {
      const float4 a4 = *(const float4*)&As2[kk][ty << 2];
      const float4 b4 = *(const float4*)&Bs2[kk][tx << 2];
      const float am[4] = {a4.x, a4.y, a4.z, a4.w};
      const float bn[4] = {b4.x, b4.y, b4.z, b4.w};
#pragma unroll
      for (int i = 0; i < 4; ++i)
#pragma unroll
        for (int j = 0; j < 4; ++j) acc[i][j] = fmaf(am[i], bn[j], acc[i][j]);
    }
  }

  if (OMODE == 0) {
    const int row0 = blockIdx.y * 64 + (ty << 2);
    const int col0 = blockIdx.x * 64 + (tx << 2);
    float4 bb4 = make_float4(0.f, 0.f, 0.f, 0.f);
    if (BIAS) bb4 = *(const float4*)&bias[col0];
#pragma unroll
    for (int i = 0; i < 4; ++i) {
      float4 o;
      o.x = acc[i][0] + bb4.x;
      o.y = acc[i][1] + bb4.y;
      o.z = acc[i][2] + bb4.z;
      o.w = acc[i][3] + bb4.w;
      *(float4*)&C[(long)(row0 + i) * ldc + col0] = o;
    }
  } else {
#pragma unroll
    for (int i = 0; i < 4; ++i) {
      const int gr = blockIdx.y * 64 + (ty << 2) + i;
      const int b = gr >> 10;
      const int e = gr & 1023;
#pragma unroll
      for (int j = 0; j < 4; ++j) {
        const int col = blockIdx.x * 64 + (tx << 2) + j;
        C[(long)b * (ATTN_A * ENC_LEN) + (long)col * ENC_LEN + e] = acc[i][j];
      }
    }
  }
}

__global__ __launch_bounds__(256) void logits_fb(const float* __restrict__ peT,
                                                 const float* __restrict__ pd,
                                                 const float* __restrict__ v,
                                                 float* __restrict__ out) {
  const int tid = threadIdx.x;
  const int e = blockIdx.x * 256 + tid;
  const int d0 = blockIdx.y * 8;
  const int b = blockIdx.z;

  __shared__ float cpd[ATTN_A][8];
  __shared__ float vv[ATTN_A];

  {
    const int a = tid;
#pragma unroll
    for (int dd = 0; dd < 8; ++dd)
      cpd[a][dd] = C2F * pd[((b * DEC_LEN + d0 + dd) * ATTN_A) + a];
    vv[a] = -2.0f * v[a];
  }
  __syncthreads();

  float acc[8] = {0.f, 0.f, 0.f, 0.f, 0.f, 0.f, 0.f, 0.f};
  const float* pe = peT + (long)b * (ATTN_A * ENC_LEN) + e;

  for (int a = 0; a < ATTN_A; a += 4) {
    float pes[4];
#pragma unroll
    for (int u = 0; u < 4; ++u) pes[u] = pe[(long)(a + u) * ENC_LEN];
#pragma unroll
    for (int u = 0; u < 4; ++u) {
      const float cpe = C2F * pes[u];
      const float vu = vv[a + u];
      const float4 c0 = *(const float4*)&cpd[a + u][0];
      const float4 c1 = *(const float4*)&cpd[a + u][4];
      const float cd[8] = {c0.x, c0.y, c0.z, c0.w, c1.x, c1.y, c1.z, c1.w};
#pragma unroll
      for (int dd = 0; dd < 8; ++dd) {
        const float x = cd[dd] + cpe;
        const float ex = __builtin_amdgcn_exp2f(x);
        const float r = __builtin_amdgcn_rcpf(ex + 1.0f);
        acc[dd] = fmaf(vu, r, acc[dd]);
      }
    }
  }

  const long base = ((long)(b * DEC_LEN + d0) * ENC_LEN) + e;
#pragma unroll
  for (int dd = 0; dd < 8; ++dd) out[base + (long)dd * ENC_LEN] = acc[dd];
}

__global__ __launch_bounds__(256) void softmax_fb(float* __restrict__ attn,
                                                  const float* __restrict__ mask) {
  const int row = blockIdx.x;
  const int b = row >> 8;
  const int tid = threadIdx.x;
  float* rp = attn + (long)row * ENC_LEN;
  const float* mp = mask + b * ENC_LEN;

  float l[4], m[4];
#pragma unroll
  for (int j = 0; j < 4; ++j) {
    l[j] = rp[tid + 256 * j];
    m[j] = mp[tid + 256 * j];
  }

  __shared__ float redmax[4];
  __shared__ float redsum[4];
  const int lane = tid & 63;
  const int wid = tid >> 6;

  float tm = fmaxf(fmaxf(l[0], l[1]), fmaxf(l[2], l[3]));
#pragma unroll
  for (int off = 1; off < 64; off <<= 1) tm = fmaxf(tm, __shfl_xor(tm, off, 64));
  if (lane == 0) redmax[wid] = tm;
  __syncthreads();
  const float rmax = fmaxf(fmaxf(redmax[0], redmax[1]), fmaxf(redmax[2], redmax[3]));

  const float LOG2E = 1.4426950408889634f;
  float p[4];
  float ts = 0.f;
#pragma unroll
  for (int j = 0; j < 4; ++j) {
    p[j] = __builtin_amdgcn_exp2f((l[j] - rmax) * LOG2E) * m[j];
    ts += p[j];
  }
#pragma unroll
  for (int off = 1; off < 64; off <<= 1) ts += __shfl_xor(ts, off, 64);
  if (lane == 0) redsum[wid] = ts;
  __syncthreads();
  const float rsum = redsum[0] + redsum[1] + redsum[2] + redsum[3];

  const float inv = 1.0f / rsum;
#pragma unroll
  for (int j = 0; j < 4; ++j) rp[tid + 256 * j] = p[j] * inv;
}

// ---------------------------------------------------------------------------
extern "C" void kernel_launch(void* const* d_in, const int* in_sizes, int n_in,
                              void* d_out, int out_size, void* d_ws, size_t ws_size,
                              hipStream_t stream) {
  const float* enc = (const float*)d_in[0];
  const float* dec = (const float*)d_in[1];
  const float* mask = (const float*)d_in[2];
  const float* Wh = (const float*)d_in[3];
  const float* Ws = (const float*)d_in[4];
  const float* bs = (const float*)d_in[5];
  const float* v = (const float*)d_in[6];

  float* ctx = (float*)d_out;                      // [4,256,1024]
  float* attn = ctx + (long)BB * DEC_LEN * ENC_H;  // [4,256,1024]

  // ws layout (fast path):
  //  pdP  f32 [2][1024][256]          2 MB
  //  peP  f32 [2][4][256][1024]       8 MB
  //  p1   f32 [4][256][1024]          4 MB
  //  cP   f32 [2][4][256][1024]       8 MB
  //  encT bf16 [4][1024h][1024e]      8 MB
  //  WhT/WsT bf16 [256][1024]         1 MB
  //  encB bf16 [4][1024e][1024h]      8 MB
  //  decB bf16 [1024][1024]           2 MB
  //  attnB bf16 [4][256][1024]        2 MB
  const long N_PD = 2L * 1024 * ATTN_A;
  const long N_PE = 2L * BB * ATTN_A * ENC_LEN;
  const long N_P1 = (long)BB * DEC_LEN * ENC_LEN;
  const long N_CP = 2L * BB * DEC_LEN * ENC_H;
  const long N_ENC = (long)BB * ENC_H * ENC_LEN;   // bf16 elems (encT / encB)
  const long N_W = (long)ATTN_A * ENC_H;           // bf16 elems per weight
  const long N_DEC = 1024L * ENC_H;                // bf16 elems (decB)
  const long N_ATT = (long)BB * DEC_LEN * ENC_LEN; // bf16 elems (attnB)
  const size_t FAST_WS = (N_PD + N_PE + N_P1 + N_CP) * 4 +
                         (N_ENC + 2 * N_W + N_ENC + N_DEC + N_ATT) * 2;

  if (ws_size >= FAST_WS) {
    float* pdP = (float*)d_ws;
    float* peP = pdP + N_PD;
    float* p1 = peP + N_PE;
    float* cP = p1 + N_P1;
    unsigned short* encT = (unsigned short*)(cP + N_CP);
    unsigned short* WhT = encT + N_ENC;
    unsigned short* WsT = WhT + N_W;
    unsigned short* encB = WsT + N_W;
    unsigned short* decB = encB + N_ENC;
    unsigned short* attnB = decB + N_DEC;

    // 1) all transposes + bf16 conversions
    prep_k<<<dim3(1408, 1, 1), 256, 0, stream>>>(Wh, Ws, enc, dec, WhT, WsT, encT,
                                                 encB, decB);
    // 2) K-split fused projections (all-bf16 operands)
    pgemm<<<dim3(4, 80, 2), 256, 0, stream>>>(decB, encB, WsT, WhT, pdP, peP);
    // 3) logits partials, batched-rcp
    logits_k<<<dim3(4, 32, BB * 2), 256, 0, stream>>>(peP, pdP, v, bs, attn, p1);
    // 4) masked softmax -> attn (fp32) + attnB (bf16)
    softmax2_k<<<dim3(BB * DEC_LEN, 1, 1), 256, 0, stream>>>(attn, p1, mask, attnB);
    // 5) K-split ctx GEMM
    cgemm<<<dim3(16, 4, BB * 2), 256, 0, stream>>>(attnB, encT, cP);
    // 6) ctx = cP0 + cP1
    creduce<<<dim3(1024, 1, 1), 256, 0, stream>>>(cP, ctx);
  } else {
    // fallback: proven fp32 path (5 MB ws)
    float* pd = (float*)d_ws;
    float* peT = pd + (long)BB * DEC_LEN * ATTN_A;

    gemm64<0, true><<<dim3(ATTN_A / 64, (BB * DEC_LEN) / 64, 1), 256, 0, stream>>>(
        dec, Ws, bs, pd, ENC_H, ENC_H, ATTN_A, ATTN_A, 0, 0, 0);
    gemm64<1, false><<<dim3(ATTN_A / 64, (BB * ENC_LEN) / 64, 1), 256, 0, stream>>>(
        enc, Wh, nullptr, peT, ENC_H, ENC_H, ATTN_A, 0, 0, 0, 0);
    logits_fb<<<dim3(ENC_LEN / 256, DEC_LEN / 8, BB), 256, 0, stream>>>(peT, pd, v,
                                                                        attn);
    softmax_fb<<<dim3(BB * DEC_LEN, 1, 1), 256, 0, stream>>>(attn, mask);
    gemm64<0, false><<<dim3(ENC_H / 64, DEC_LEN / 64, BB), 256, 0, stream>>>(
        attn, enc, nullptr, ctx, ENC_LEN, ENC_LEN, ENC_H, ENC_H,
        (long)DEC_LEN * ENC_LEN, (long)ENC_LEN * ENC_H, (long)DEC_LEN * ENC_H);
  }
}